// Round 7
// baseline (165.012 us; speedup 1.0000x reference)
//
#include <hip/hip_runtime.h>
#include <cstdint>
#include <cstddef>

// ---------------------------------------------------------------------------
// Attention_Param_sharing_Kv_sharing: B=4, C=256, H=W=64 (N=4096), KD=16,
// NH=8, DH=128.  qk projection shared between Q and K (Gram matrix), one KV
// head shared across 8 heads -> O = softmax(qk^T qk) @ V, V in R^{N x 128}.
//
// R4: 175 us, attn 137 us @ 11% occupancy (latency-bound).
// R5: global key-split x4 regressed (L2 flush from 33 MB partial writes).
// R6: in-block key-split x4: occupancy 11->20.5% but time flat (141 us);
//     per-wave issue util unchanged -> residency still capped (34 KB LDS,
//     92+32 regs).
// R7: occupancy experiment at constant algorithm: LDS 34->17.9 KB (fp16
//     partials, p_lds region reused as partial buffer), vb hoist halved
//     (32 fewer VGPRs), __launch_bounds__(256,4), all-wave merge epilogue.
// ---------------------------------------------------------------------------

typedef __attribute__((ext_vector_type(4))) float f32x4;
typedef __attribute__((ext_vector_type(8))) _Float16 half8;
typedef __attribute__((ext_vector_type(8))) unsigned short ushort8;

#define N_SP 4096
#define CIN  256
#define KDIM 16
#define DHV  128

__device__ __forceinline__ unsigned short f2h(float f) {
    _Float16 h = (_Float16)f;             // RNE
    return __builtin_bit_cast(unsigned short, h);
}

__device__ __forceinline__ float h2f(unsigned short u) {
    return (float)__builtin_bit_cast(_Float16, u);
}

__device__ __forceinline__ f32x4 mfma16(ushort8 a, ushort8 b, f32x4 c) {
    return __builtin_amdgcn_mfma_f32_16x16x32_f16(
        __builtin_bit_cast(half8, a), __builtin_bit_cast(half8, b), c, 0, 0, 0);
}

// ---------------------------------------------------------------------------
// Kernel 0: fold BN into weights (unchanged).
// ---------------------------------------------------------------------------
__global__ __launch_bounds__(256) void fold_weights(
    const float* __restrict__ w_qk, const float* __restrict__ g_qk,
    const float* __restrict__ b_qk, const float* __restrict__ m_qk,
    const float* __restrict__ v_qk,
    const float* __restrict__ w_v, const float* __restrict__ g_v,
    const float* __restrict__ b_v, const float* __restrict__ m_v,
    const float* __restrict__ v_v,
    const float* __restrict__ w_p, const float* __restrict__ g_p,
    const float* __restrict__ b_p, const float* __restrict__ m_p,
    const float* __restrict__ v_p,
    unsigned short* __restrict__ wf1, float* __restrict__ shift1,
    unsigned short* __restrict__ wpf, float* __restrict__ shiftp)
{
    int row = blockIdx.x;
    int t   = threadIdx.x;
    if (row < 144) {
        float s, sh; const float* src;
        if (row < KDIM) {
            s  = g_qk[row] * rsqrtf(v_qk[row] + 1e-5f);
            sh = b_qk[row] - m_qk[row] * s;
            src = w_qk + row * CIN;
        } else {
            int o = row - KDIM;
            s  = g_v[o] * rsqrtf(v_v[o] + 1e-5f);
            sh = b_v[o] - m_v[o] * s;
            src = w_v + o * CIN;
        }
        wf1[row * CIN + t] = f2h(src[t] * s);
        if (t == 0) shift1[row] = sh;
    } else {
        int o = row - 144;
        float s = g_p[o] * rsqrtf(v_p[o] + 1e-5f);
        if (t < DHV) wpf[o * DHV + t] = f2h(w_p[o * DHV + t] * s);
        if (t == 0) shiftp[o] = b_p[o] - m_p[o] * s;
    }
}

// ---------------------------------------------------------------------------
// Kernel 1: projection GEMM (unchanged from R6: x read exactly once).
// ---------------------------------------------------------------------------
__global__ __launch_bounds__(256) void proj_qkv(
    const float* __restrict__ x,
    const unsigned short* __restrict__ wf1, const float* __restrict__ shift1,
    unsigned short* __restrict__ qkT, unsigned short* __restrict__ Vt)
{
    const int b  = blockIdx.y;
    const int n0 = blockIdx.x * 64;
    const int tid  = threadIdx.x;
    const int w    = tid >> 6;
    const int lane = tid & 63;
    const int lg   = lane >> 4;
    const int lr   = lane & 15;
    const int n    = n0 + w * 16 + lr;

    const float* xb = x + (size_t)b * CIN * N_SP;
    f32x4 acc[9];
#pragma unroll
    for (int i = 0; i < 9; ++i) acc[i] = (f32x4){0.f, 0.f, 0.f, 0.f};

    for (int ks = 0; ks < 8; ++ks) {
        const int cbase = ks * 32 + lg * 8;
        ushort8 bx;
#pragma unroll
        for (int j = 0; j < 8; ++j) {
            float xv = xb[(size_t)(cbase + j) * N_SP + n];
            bx[j] = f2h(xv);
        }
#pragma unroll
        for (int ot = 0; ot < 9; ++ot) {
            ushort8 a = *(const ushort8*)(wf1 + (ot * 16 + lr) * CIN + cbase);
            acc[ot] = mfma16(a, bx, acc[ot]);
        }
    }

#pragma unroll
    for (int ot = 0; ot < 9; ++ot)
#pragma unroll
        for (int r = 0; r < 4; ++r) {
            int o = ot * 16 + lg * 4 + r;
            float val = acc[ot][r] + shift1[o];
            unsigned short hv = f2h(val);
            if (o < KDIM) qkT[((size_t)b * N_SP + n) * 32 + o] = hv;
            else          Vt[((size_t)b * DHV + (o - KDIM)) * N_SP + n] = hv;
        }

    // zero the K-padding columns 16..31 of qkT for this (b, n-tile)
    {
        int n_l  = tid >> 2;
        int part = tid & 3;
        unsigned long long* p = (unsigned long long*)
            (qkT + ((size_t)b * N_SP + n0 + n_l) * 32 + 16 + part * 4);
        *p = 0ULL;
    }
}

// ---------------------------------------------------------------------------
// Kernel 2: flash attention, in-block key-split, low-footprint.
// Grid (256, B), 256 thr = 4 waves.  Block owns 16 q-rows; wave w processes
// keys [w*1024, (w+1)*1024).  Each wave's shbuf[w] region serves two phases:
// (loop) P-transpose tile [16][72 of 136];  (epilogue) fp16 partial O
// [16][128 of 136].  One barrier; all 4 waves merge 4 rows each.
// ---------------------------------------------------------------------------
__global__ __launch_bounds__(256, 4) void attn_kernel(
    const unsigned short* __restrict__ qkT,
    const unsigned short* __restrict__ Vt,
    unsigned short* __restrict__ xx)
{
    const int b  = blockIdx.y;
    const int q0 = blockIdx.x * 16;
    const int tid  = threadIdx.x;
    const int w    = tid >> 6;               // key-split index 0..3
    const int lane = tid & 63;
    const int lg   = lane >> 4;
    const int lr   = lane & 15;

    const unsigned short* qk_b = qkT + (size_t)b * N_SP * 32;
    const unsigned short* vt_b = Vt  + (size_t)b * DHV * N_SP;

    const int kbeg = w * (N_SP / 4);
    const int kend = kbeg + (N_SP / 4);

    const ushort8 aq = *(const ushort8*)(qk_b + (size_t)(q0 + lr) * 32 + lg * 8);

    f32x4 acc[8];
#pragma unroll
    for (int i = 0; i < 8; ++i) acc[i] = (f32x4){0.f, 0.f, 0.f, 0.f};
    float m_r[4] = {-__builtin_inff(), -__builtin_inff(),
                    -__builtin_inff(), -__builtin_inff()};
    float l_r[4] = {0.f, 0.f, 0.f, 0.f};     // per-lane partial sums

    // per-wave dual-use region: [16][0..71] = P-transpose, later [16][0..127]
    // = fp16 partial O.  Stride 136 ushort (272 B) for bank spread.
    __shared__ __align__(16) unsigned short shbuf[4][16][136];   // 17408 B
    __shared__ float pm[4][16], pl[4][16];                       // 512 B

    const f32x4 zero4 = {0.f, 0.f, 0.f, 0.f};

    for (int k0 = kbeg; k0 < kend; k0 += 64) {
        // ---- S = Q K^T for this wave's 16 queries x 64 keys -------------
        f32x4 s[4];
#pragma unroll
        for (int t = 0; t < 4; ++t) {
            ushort8 bk = *(const ushort8*)(qk_b + (size_t)(k0 + t * 16 + lr) * 32 + lg * 8);
            s[t] = mfma16(aq, bk, zero4);
        }

        // ---- hoist first half of V (ks=0); second half issues under PV0 --
        ushort8 vb[8];
#pragma unroll
        for (int nn = 0; nn < 8; ++nn)
            vb[nn] = *(const ushort8*)
                (vt_b + (size_t)(nn * 16 + lr) * N_SP + k0 + lg * 8);

        // ---- online softmax (rows = lg*4+r, max-reduce over lane&15) -----
        float sc_r[4];
#pragma unroll
        for (int r = 0; r < 4; ++r) {
            float mx = fmaxf(fmaxf(s[0][r], s[1][r]), fmaxf(s[2][r], s[3][r]));
            mx = fmaxf(mx, __shfl_xor(mx, 1));
            mx = fmaxf(mx, __shfl_xor(mx, 2));
            mx = fmaxf(mx, __shfl_xor(mx, 4));
            mx = fmaxf(mx, __shfl_xor(mx, 8));
            float mnew = fmaxf(m_r[r], mx);
            float sc = __expf(m_r[r] - mnew);     // first iter: exp(-inf)=0
            float rs = 0.f;
#pragma unroll
            for (int t = 0; t < 4; ++t) {
                float p = __expf(s[t][r] - mnew);
                s[t][r] = p;
                rs += p;
            }
            l_r[r] = l_r[r] * sc + rs;            // deferred: per-lane partial
            m_r[r] = mnew;
            sc_r[r] = sc;
        }

        // ---- rescale accumulator ----------------------------------------
#pragma unroll
        for (int nn = 0; nn < 8; ++nn)
#pragma unroll
            for (int r = 0; r < 4; ++r) acc[nn][r] *= sc_r[r];

        // ---- P -> LDS transpose (own wave region, no barrier needed) -----
#pragma unroll
        for (int t = 0; t < 4; ++t)
#pragma unroll
            for (int r = 0; r < 4; ++r)
                shbuf[w][lg * 4 + r][t * 16 + lr] = f2h(s[t][r]);

        // ---- O += P @ V  (ks=0 with hoisted vb, then reload for ks=1) ----
        {
            ushort8 pa = *(const ushort8*)(&shbuf[w][lr][lg * 8]);
#pragma unroll
            for (int nn = 0; nn < 8; ++nn)
                acc[nn] = mfma16(pa, vb[nn], acc[nn]);
        }
#pragma unroll
        for (int nn = 0; nn < 8; ++nn)
            vb[nn] = *(const ushort8*)
                (vt_b + (size_t)(nn * 16 + lr) * N_SP + k0 + 32 + lg * 8);
        {
            ushort8 pa = *(const ushort8*)(&shbuf[w][lr][32 + lg * 8]);
#pragma unroll
            for (int nn = 0; nn < 8; ++nn)
                acc[nn] = mfma16(pa, vb[nn], acc[nn]);
        }
    }

    // ---- finish deferred l: reduce across lane&15 ------------------------
#pragma unroll
    for (int r = 0; r < 4; ++r) {
        float rs = l_r[r];
        rs += __shfl_xor(rs, 1);
        rs += __shfl_xor(rs, 2);
        rs += __shfl_xor(rs, 4);
        rs += __shfl_xor(rs, 8);
        l_r[r] = rs;
    }

    // ---- publish fp16 partials into OWN region (no pre-barrier needed) ---
#pragma unroll
    for (int r = 0; r < 4; ++r) {
        int row = lg * 4 + r;
#pragma unroll
        for (int nn = 0; nn < 8; ++nn)
            shbuf[w][row][nn * 16 + lr] = f2h(acc[nn][r]);
        if (lr == 0) { pm[w][row] = m_r[r]; pl[w][row] = l_r[r]; }
    }
    __syncthreads();

    // ---- all waves: exp-weighted merge, normalize, relu, store -----------
    {
        const int row = w * 4 + lg;           // wave w merges rows 4w..4w+3
        float M = fmaxf(fmaxf(pm[0][row], pm[1][row]),
                        fmaxf(pm[2][row], pm[3][row]));
        float ws0 = __expf(pm[0][row] - M);
        float ws1 = __expf(pm[1][row] - M);
        float ws2 = __expf(pm[2][row] - M);
        float ws3 = __expf(pm[3][row] - M);
        float L = pl[0][row] * ws0 + pl[1][row] * ws1
                + pl[2][row] * ws2 + pl[3][row] * ws3;
        float inv = 1.0f / L;
        const size_t xoff = (size_t)b * N_SP * DHV + (size_t)(q0 + row) * DHV;
#pragma unroll
        for (int nn = 0; nn < 8; ++nn) {
            int d = nn * 16 + lr;
            float o = h2f(shbuf[0][row][d]) * ws0
                    + h2f(shbuf[1][row][d]) * ws1
                    + h2f(shbuf[2][row][d]) * ws2
                    + h2f(shbuf[3][row][d]) * ws3;
            xx[xoff + d] = f2h(fmaxf(o * inv, 0.f));
        }
    }
}

// ---------------------------------------------------------------------------
// Kernel 3: output projection (unchanged).
// ---------------------------------------------------------------------------
__global__ __launch_bounds__(256) void proj_out(
    const unsigned short* __restrict__ xx,
    const unsigned short* __restrict__ wpf, const float* __restrict__ shiftp,
    float* __restrict__ out)
{
    const int b  = blockIdx.z;
    const int n0 = blockIdx.y * 64;
    const int o0 = blockIdx.x * 64 + (threadIdx.x >> 6) * 16;
    const int lane = threadIdx.x & 63;
    const int lg   = lane >> 4;
    const int lr   = lane & 15;

    f32x4 acc[4];
#pragma unroll
    for (int i = 0; i < 4; ++i) acc[i] = (f32x4){0.f, 0.f, 0.f, 0.f};

    const unsigned short* xb = xx + (size_t)b * N_SP * DHV;

    for (int ks = 0; ks < 4; ++ks) {
        ushort8 a = *(const ushort8*)(wpf + (size_t)(o0 + lr) * DHV + ks * 32 + lg * 8);
#pragma unroll
        for (int nt = 0; nt < 4; ++nt) {
            ushort8 bfr = *(const ushort8*)
                (xb + (size_t)(n0 + nt * 16 + lr) * DHV + ks * 32 + lg * 8);
            acc[nt] = mfma16(a, bfr, acc[nt]);
        }
    }

#pragma unroll
    for (int nt = 0; nt < 4; ++nt)
#pragma unroll
        for (int r = 0; r < 4; ++r) {
            int o = o0 + lg * 4 + r;
            out[((size_t)b * CIN + o) * N_SP + n0 + nt * 16 + lr]
                = acc[nt][r] + shiftp[o];
        }
}

// ---------------------------------------------------------------------------
extern "C" void kernel_launch(void* const* d_in, const int* in_sizes, int n_in,
                              void* d_out, int out_size, void* d_ws, size_t ws_size,
                              hipStream_t stream)
{
    const float* x    = (const float*)d_in[0];
    const float* w_qk = (const float*)d_in[2];
    const float* g_qk = (const float*)d_in[3];
    const float* b_qk = (const float*)d_in[4];
    const float* m_qk = (const float*)d_in[5];
    const float* v_qk = (const float*)d_in[6];
    const float* w_v  = (const float*)d_in[7];
    const float* g_v  = (const float*)d_in[8];
    const float* b_v  = (const float*)d_in[9];
    const float* m_v  = (const float*)d_in[10];
    const float* v_v  = (const float*)d_in[11];
    const float* w_p  = (const float*)d_in[12];
    const float* g_p  = (const float*)d_in[13];
    const float* b_p  = (const float*)d_in[14];
    const float* m_p  = (const float*)d_in[15];
    const float* v_p  = (const float*)d_in[16];

    char* ws = (char*)d_ws;
    unsigned short* qkT = (unsigned short*)(ws);                    // 1 MB
    unsigned short* Vt  = (unsigned short*)(ws + (1u << 20));       // 4 MB
    unsigned short* xxb = (unsigned short*)(ws + (5u << 20));       // 4 MB
    unsigned short* wf1 = (unsigned short*)(ws + (9u << 20));       // 72 KB
    float* shift1       = (float*)(ws + (9u << 20) + 80 * 1024);    // 576 B
    unsigned short* wpf = (unsigned short*)(ws + (9u << 20) + 84 * 1024); // 64 KB
    float* shiftp       = (float*)(ws + (9u << 20) + 148 * 1024);   // 1 KB

    fold_weights<<<400, 256, 0, stream>>>(
        w_qk, g_qk, b_qk, m_qk, v_qk,
        w_v, g_v, b_v, m_v, v_v,
        w_p, g_p, b_p, m_p, v_p,
        wf1, shift1, wpf, shiftp);

    proj_qkv<<<dim3(64, 4), 256, 0, stream>>>(x, wf1, shift1, qkT, Vt);

    attn_kernel<<<dim3(256, 4), 256, 0, stream>>>(qkT, Vt, xxb);

    proj_out<<<dim3(4, 64, 4), 256, 0, stream>>>(xxb, wpf, shiftp, (float*)d_out);
}

// Round 8
// 138.544 us; speedup vs baseline: 1.1910x; 1.1910x over previous
//
#include <hip/hip_runtime.h>
#include <cstdint>
#include <cstddef>

// ---------------------------------------------------------------------------
// Attention_Param_sharing_Kv_sharing: B=4, C=256, H=W=64 (N=4096), KD=16,
// NH=8, DH=128.  qk projection shared between Q and K (Gram matrix), one KV
// head shared across 8 heads -> O = softmax(qk^T qk) @ V, V in R^{N x 128}.
//
// R4/R6/R7: attn time flat at ~140 us across occupancy 11/20/38% ->
//   throughput cap of ~1200 cyc/wave-tile of shared CU resource (320 L1
//   lines of redundant per-wave K/V traffic + 34 LDS-pipe ops).
// R8: canonical 2-phase flash: K/V tile staged ONCE per block into
//   double-buffered LDS via global_load_lds (pre-swizzled source, swizzled
//   ds_read -- rule 21), shared by all 4 waves.  Line traffic /4.
//   Softmax/P-LDS/PV/epilogue identical to verified R4/R7 code.
// ---------------------------------------------------------------------------

typedef __attribute__((ext_vector_type(4))) float f32x4;
typedef __attribute__((ext_vector_type(8))) _Float16 half8;
typedef __attribute__((ext_vector_type(8))) unsigned short ushort8;

#define N_SP 4096
#define CIN  256
#define KDIM 16
#define DHV  128

__device__ __forceinline__ unsigned short f2h(float f) {
    _Float16 h = (_Float16)f;             // RNE
    return __builtin_bit_cast(unsigned short, h);
}

__device__ __forceinline__ f32x4 mfma16(ushort8 a, ushort8 b, f32x4 c) {
    return __builtin_amdgcn_mfma_f32_16x16x32_f16(
        __builtin_bit_cast(half8, a), __builtin_bit_cast(half8, b), c, 0, 0, 0);
}

// ---------------------------------------------------------------------------
// Kernel 0: fold BN into weights (unchanged).
// ---------------------------------------------------------------------------
__global__ __launch_bounds__(256) void fold_weights(
    const float* __restrict__ w_qk, const float* __restrict__ g_qk,
    const float* __restrict__ b_qk, const float* __restrict__ m_qk,
    const float* __restrict__ v_qk,
    const float* __restrict__ w_v, const float* __restrict__ g_v,
    const float* __restrict__ b_v, const float* __restrict__ m_v,
    const float* __restrict__ v_v,
    const float* __restrict__ w_p, const float* __restrict__ g_p,
    const float* __restrict__ b_p, const float* __restrict__ m_p,
    const float* __restrict__ v_p,
    unsigned short* __restrict__ wf1, float* __restrict__ shift1,
    unsigned short* __restrict__ wpf, float* __restrict__ shiftp)
{
    int row = blockIdx.x;
    int t   = threadIdx.x;
    if (row < 144) {
        float s, sh; const float* src;
        if (row < KDIM) {
            s  = g_qk[row] * rsqrtf(v_qk[row] + 1e-5f);
            sh = b_qk[row] - m_qk[row] * s;
            src = w_qk + row * CIN;
        } else {
            int o = row - KDIM;
            s  = g_v[o] * rsqrtf(v_v[o] + 1e-5f);
            sh = b_v[o] - m_v[o] * s;
            src = w_v + o * CIN;
        }
        wf1[row * CIN + t] = f2h(src[t] * s);
        if (t == 0) shift1[row] = sh;
    } else {
        int o = row - 144;
        float s = g_p[o] * rsqrtf(v_p[o] + 1e-5f);
        if (t < DHV) wpf[o * DHV + t] = f2h(w_p[o * DHV + t] * s);
        if (t == 0) shiftp[o] = b_p[o] - m_p[o] * s;
    }
}

// ---------------------------------------------------------------------------
// Kernel 1: projection GEMM (unchanged from R6: x read exactly once).
// ---------------------------------------------------------------------------
__global__ __launch_bounds__(256) void proj_qkv(
    const float* __restrict__ x,
    const unsigned short* __restrict__ wf1, const float* __restrict__ shift1,
    unsigned short* __restrict__ qkT, unsigned short* __restrict__ Vt)
{
    const int b  = blockIdx.y;
    const int n0 = blockIdx.x * 64;
    const int tid  = threadIdx.x;
    const int w    = tid >> 6;
    const int lane = tid & 63;
    const int lg   = lane >> 4;
    const int lr   = lane & 15;
    const int n    = n0 + w * 16 + lr;

    const float* xb = x + (size_t)b * CIN * N_SP;
    f32x4 acc[9];
#pragma unroll
    for (int i = 0; i < 9; ++i) acc[i] = (f32x4){0.f, 0.f, 0.f, 0.f};

    for (int ks = 0; ks < 8; ++ks) {
        const int cbase = ks * 32 + lg * 8;
        ushort8 bx;
#pragma unroll
        for (int j = 0; j < 8; ++j) {
            float xv = xb[(size_t)(cbase + j) * N_SP + n];
            bx[j] = f2h(xv);
        }
#pragma unroll
        for (int ot = 0; ot < 9; ++ot) {
            ushort8 a = *(const ushort8*)(wf1 + (ot * 16 + lr) * CIN + cbase);
            acc[ot] = mfma16(a, bx, acc[ot]);
        }
    }

#pragma unroll
    for (int ot = 0; ot < 9; ++ot)
#pragma unroll
        for (int r = 0; r < 4; ++r) {
            int o = ot * 16 + lg * 4 + r;
            float val = acc[ot][r] + shift1[o];
            unsigned short hv = f2h(val);
            if (o < KDIM) qkT[((size_t)b * N_SP + n) * 32 + o] = hv;
            else          Vt[((size_t)b * DHV + (o - KDIM)) * N_SP + n] = hv;
        }

    // zero the K-padding columns 16..31 of qkT for this (b, n-tile)
    {
        int n_l  = tid >> 2;
        int part = tid & 3;
        unsigned long long* p = (unsigned long long*)
            (qkT + ((size_t)b * N_SP + n0 + n_l) * 32 + 16 + part * 4);
        *p = 0ULL;
    }
}

// ---------------------------------------------------------------------------
// Stage one 64-key tile (K: 64x32 halves = 4KB, V: 128x64 halves = 16KB)
// into LDS via global_load_lds, 20 x 1KB chunks, wave w issues chunks
// [w*5, w*5+5).  Source pre-swizzled so the linear LDS write lands data
// such that the swizzled ds_read is bank-spread (rule 21):
//   K: lds[row][c4] = K[row][c4 ^ (row&3)]   (c4: 16B slots of 64B row)
//   V: lds[row][c8] = V[row][c8 ^ (row&7)]   (c8: 16B slots of 128B row)
// ---------------------------------------------------------------------------
__device__ __forceinline__ void stage_tile(
    const unsigned short* __restrict__ qk_b,
    const unsigned short* __restrict__ vt_b,
    unsigned short* k_l, unsigned short* v_l,
    int k0, int w, int lane)
{
#pragma unroll
    for (int s = 0; s < 5; ++s) {
        const int idx = w * 5 + s;
        if (idx < 4) {
            // K chunk idx: rows idx*16 .. idx*16+15
            int row = idx * 16 + (lane >> 2);
            int c4  = (lane & 3) ^ ((lane >> 2) & 3);
            const unsigned short* src = qk_b + (size_t)(k0 + row) * 32 + c4 * 8;
            __builtin_amdgcn_global_load_lds(
                (const __attribute__((address_space(1))) void*)src,
                (__attribute__((address_space(3))) void*)(k_l + idx * 512),
                16, 0, 0);
        } else {
            // V chunk vi: rows vi*8 .. vi*8+7
            int vi  = idx - 4;
            int row = vi * 8 + (lane >> 3);
            int c8  = (lane & 7) ^ (lane >> 3);      // (row&7) == lane>>3
            const unsigned short* src = vt_b + (size_t)row * N_SP + k0 + c8 * 8;
            __builtin_amdgcn_global_load_lds(
                (const __attribute__((address_space(1))) void*)src,
                (__attribute__((address_space(3))) void*)(v_l + vi * 512),
                16, 0, 0);
        }
    }
}

// ---------------------------------------------------------------------------
// Kernel 2: flash attention, LDS-shared K/V tiles, double-buffered.
// Grid (64, B), 256 thr = 4 waves.  Block owns 64 q-rows (wave w: 16);
// loops all 64 key-tiles; K/V staged once per block per tile.
// Softmax / P-LDS / PV / epilogue identical to verified R4/R7 code.
// ---------------------------------------------------------------------------
__global__ __launch_bounds__(256) void attn_kernel(
    const unsigned short* __restrict__ qkT,
    const unsigned short* __restrict__ Vt,
    unsigned short* __restrict__ xx)
{
    const int b  = blockIdx.y;
    const int q0 = blockIdx.x * 64;
    const int tid  = threadIdx.x;
    const int w    = tid >> 6;
    const int lane = tid & 63;
    const int lg   = lane >> 4;
    const int lr   = lane & 15;

    const unsigned short* qk_b = qkT + (size_t)b * N_SP * 32;
    const unsigned short* vt_b = Vt  + (size_t)b * DHV * N_SP;
    const int qrow = q0 + w * 16;

    const ushort8 aq = *(const ushort8*)(qk_b + (size_t)(qrow + lr) * 32 + lg * 8);

    f32x4 acc[8];
#pragma unroll
    for (int i = 0; i < 8; ++i) acc[i] = (f32x4){0.f, 0.f, 0.f, 0.f};
    float m_r[4] = {-__builtin_inff(), -__builtin_inff(),
                    -__builtin_inff(), -__builtin_inff()};
    float l_r[4] = {0.f, 0.f, 0.f, 0.f};     // per-lane partial sums (deferred)

    __shared__ __align__(16) unsigned short k_lds[2][64 * 32];   //  2 x 4 KB
    __shared__ __align__(16) unsigned short v_lds[2][128 * 64];  //  2 x 16 KB
    __shared__ __align__(16) unsigned short p_lds[4][16][72];    //  9.2 KB

    const f32x4 zero4 = {0.f, 0.f, 0.f, 0.f};

    // prologue: stage tile 0 into buffer 0
    stage_tile(qk_b, vt_b, k_lds[0], v_lds[0], 0, w, lane);

    for (int t = 0; t < 64; ++t) {
        const int cur = t & 1;
        __syncthreads();   // drains vmcnt -> buf[cur] ready; prev reads done
        if (t < 63)
            stage_tile(qk_b, vt_b, k_lds[cur ^ 1], v_lds[cur ^ 1],
                       (t + 1) * 64, w, lane);

        const unsigned short* kl = k_lds[cur];
        const unsigned short* vl = v_lds[cur];

        // ---- S = Q K^T for this wave's 16 queries x 64 keys (K from LDS) -
        f32x4 s[4];
#pragma unroll
        for (int tt = 0; tt < 4; ++tt) {
            int row = tt * 16 + lr;
            ushort8 bk = *(const ushort8*)(kl + row * 32 + ((lg ^ (lr & 3)) << 3));
            s[tt] = mfma16(aq, bk, zero4);
        }

        // ---- online softmax (rows = lg*4+r, max-reduce over lane&15) -----
        float sc_r[4];
#pragma unroll
        for (int r = 0; r < 4; ++r) {
            float mx = fmaxf(fmaxf(s[0][r], s[1][r]), fmaxf(s[2][r], s[3][r]));
            mx = fmaxf(mx, __shfl_xor(mx, 1));
            mx = fmaxf(mx, __shfl_xor(mx, 2));
            mx = fmaxf(mx, __shfl_xor(mx, 4));
            mx = fmaxf(mx, __shfl_xor(mx, 8));
            float mnew = fmaxf(m_r[r], mx);
            float sc = __expf(m_r[r] - mnew);     // first iter: exp(-inf)=0
            float rs = 0.f;
#pragma unroll
            for (int tt = 0; tt < 4; ++tt) {
                float p = __expf(s[tt][r] - mnew);
                s[tt][r] = p;
                rs += p;
            }
            l_r[r] = l_r[r] * sc + rs;            // deferred cross-lane sum
            m_r[r] = mnew;
            sc_r[r] = sc;
        }

        // ---- rescale accumulator ----------------------------------------
#pragma unroll
        for (int nn = 0; nn < 8; ++nn)
#pragma unroll
            for (int r = 0; r < 4; ++r) acc[nn][r] *= sc_r[r];

        // ---- P -> LDS transpose (own wave region, no barrier needed) -----
#pragma unroll
        for (int tt = 0; tt < 4; ++tt)
#pragma unroll
            for (int r = 0; r < 4; ++r)
                p_lds[w][lg * 4 + r][tt * 16 + lr] = f2h(s[tt][r]);

        // ---- O += P @ V  (V from LDS, swizzled read) ---------------------
#pragma unroll
        for (int ks = 0; ks < 2; ++ks) {
            ushort8 pa = *(const ushort8*)(&p_lds[w][lr][ks * 32 + lg * 8]);
#pragma unroll
            for (int nn = 0; nn < 8; ++nn) {
                int row = nn * 16 + lr;
                ushort8 vbf = *(const ushort8*)
                    (vl + row * 64 + ((((ks << 2) + lg) ^ (lr & 7)) << 3));
                acc[nn] = mfma16(pa, vbf, acc[nn]);
            }
        }
    }

    // ---- finish deferred l: reduce across lane&15 ------------------------
#pragma unroll
    for (int r = 0; r < 4; ++r) {
        float rs = l_r[r];
        rs += __shfl_xor(rs, 1);
        rs += __shfl_xor(rs, 2);
        rs += __shfl_xor(rs, 4);
        rs += __shfl_xor(rs, 8);
        l_r[r] = rs;
    }

    // ---- epilogue: divide, relu, store xx[b][q][128] f16 -----------------
    const size_t xoff = (size_t)b * N_SP * DHV;
#pragma unroll
    for (int r = 0; r < 4; ++r) {
        float inv = 1.0f / l_r[r];
        int q = qrow + lg * 4 + r;
#pragma unroll
        for (int nn = 0; nn < 8; ++nn) {
            float v = acc[nn][r] * inv;
            v = fmaxf(v, 0.f);
            xx[xoff + (size_t)q * DHV + nn * 16 + lr] = f2h(v);
        }
    }
}

// ---------------------------------------------------------------------------
// Kernel 3: output projection (unchanged).
// ---------------------------------------------------------------------------
__global__ __launch_bounds__(256) void proj_out(
    const unsigned short* __restrict__ xx,
    const unsigned short* __restrict__ wpf, const float* __restrict__ shiftp,
    float* __restrict__ out)
{
    const int b  = blockIdx.z;
    const int n0 = blockIdx.y * 64;
    const int o0 = blockIdx.x * 64 + (threadIdx.x >> 6) * 16;
    const int lane = threadIdx.x & 63;
    const int lg   = lane >> 4;
    const int lr   = lane & 15;

    f32x4 acc[4];
#pragma unroll
    for (int i = 0; i < 4; ++i) acc[i] = (f32x4){0.f, 0.f, 0.f, 0.f};

    const unsigned short* xb = xx + (size_t)b * N_SP * DHV;

    for (int ks = 0; ks < 4; ++ks) {
        ushort8 a = *(const ushort8*)(wpf + (size_t)(o0 + lr) * DHV + ks * 32 + lg * 8);
#pragma unroll
        for (int nt = 0; nt < 4; ++nt) {
            ushort8 bfr = *(const ushort8*)
                (xb + (size_t)(n0 + nt * 16 + lr) * DHV + ks * 32 + lg * 8);
            acc[nt] = mfma16(a, bfr, acc[nt]);
        }
    }

#pragma unroll
    for (int nt = 0; nt < 4; ++nt)
#pragma unroll
        for (int r = 0; r < 4; ++r) {
            int o = o0 + lg * 4 + r;
            out[((size_t)b * CIN + o) * N_SP + n0 + nt * 16 + lr]
                = acc[nt][r] + shiftp[o];
        }
}

// ---------------------------------------------------------------------------
extern "C" void kernel_launch(void* const* d_in, const int* in_sizes, int n_in,
                              void* d_out, int out_size, void* d_ws, size_t ws_size,
                              hipStream_t stream)
{
    const float* x    = (const float*)d_in[0];
    const float* w_qk = (const float*)d_in[2];
    const float* g_qk = (const float*)d_in[3];
    const float* b_qk = (const float*)d_in[4];
    const float* m_qk = (const float*)d_in[5];
    const float* v_qk = (const float*)d_in[6];
    const float* w_v  = (const float*)d_in[7];
    const float* g_v  = (const float*)d_in[8];
    const float* b_v  = (const float*)d_in[9];
    const float* m_v  = (const float*)d_in[10];
    const float* v_v  = (const float*)d_in[11];
    const float* w_p  = (const float*)d_in[12];
    const float* g_p  = (const float*)d_in[13];
    const float* b_p  = (const float*)d_in[14];
    const float* m_p  = (const float*)d_in[15];
    const float* v_p  = (const float*)d_in[16];

    char* ws = (char*)d_ws;
    unsigned short* qkT = (unsigned short*)(ws);                    // 1 MB
    unsigned short* Vt  = (unsigned short*)(ws + (1u << 20));       // 4 MB
    unsigned short* xxb = (unsigned short*)(ws + (5u << 20));       // 4 MB
    unsigned short* wf1 = (unsigned short*)(ws + (9u << 20));       // 72 KB
    float* shift1       = (float*)(ws + (9u << 20) + 80 * 1024);    // 576 B
    unsigned short* wpf = (unsigned short*)(ws + (9u << 20) + 84 * 1024); // 64 KB
    float* shiftp       = (float*)(ws + (9u << 20) + 148 * 1024);   // 1 KB

    fold_weights<<<400, 256, 0, stream>>>(
        w_qk, g_qk, b_qk, m_qk, v_qk,
        w_v, g_v, b_v, m_v, v_v,
        w_p, g_p, b_p, m_p, v_p,
        wf1, shift1, wpf, shiftp);

    proj_qkv<<<dim3(64, 4), 256, 0, stream>>>(x, wf1, shift1, qkT, Vt);

    attn_kernel<<<dim3(64, 4), 256, 0, stream>>>(qkT, Vt, xxb);

    proj_out<<<dim3(4, 64, 4), 256, 0, stream>>>(xxb, wpf, shiftp, (float*)d_out);
}

// Round 9
// 101.639 us; speedup vs baseline: 1.6235x; 1.3631x over previous
//
#include <hip/hip_runtime.h>
#include <cstdint>
#include <cstddef>

// ---------------------------------------------------------------------------
// Attention_Param_sharing_Kv_sharing: B=4, C=256, H=W=64 (N=4096), KD=16,
// NH=8, DH=128.  Gram-matrix attention, one shared KV head.
//
// R8: LDS-shared K/V staging (global_load_lds, pre-swizzled src): 141->111 us.
//     Still 1 wave/SIMD (grid 256 = 1 block/CU) -> ~4200 cyc/tile-period vs
//     ~1400 cyc of actual pipe work: latency fully exposed.
// R9: 8-wave blocks (512 thr), in-block key-split x2: waves 0-3 keys
//     [0,2048), waves 4-7 keys [2048,4096), per-stream double-buffered LDS
//     (99 KB).  Staging bytes unchanged; 2 waves/SIMD interleave the two
//     streams' serial chains.  Stream-1 publishes fp16 partials into the
//     dead V-buffer (R7-verified merge), stream-0 merges + stores.
//     Inner tile compute byte-identical to verified R8.
// ---------------------------------------------------------------------------

typedef __attribute__((ext_vector_type(4))) float f32x4;
typedef __attribute__((ext_vector_type(8))) _Float16 half8;
typedef __attribute__((ext_vector_type(8))) unsigned short ushort8;

#define N_SP 4096
#define CIN  256
#define KDIM 16
#define DHV  128

__device__ __forceinline__ unsigned short f2h(float f) {
    _Float16 h = (_Float16)f;             // RNE
    return __builtin_bit_cast(unsigned short, h);
}

__device__ __forceinline__ float h2f(unsigned short u) {
    return (float)__builtin_bit_cast(_Float16, u);
}

__device__ __forceinline__ f32x4 mfma16(ushort8 a, ushort8 b, f32x4 c) {
    return __builtin_amdgcn_mfma_f32_16x16x32_f16(
        __builtin_bit_cast(half8, a), __builtin_bit_cast(half8, b), c, 0, 0, 0);
}

// ---------------------------------------------------------------------------
// Kernel 0: fold BN into weights (unchanged).
// ---------------------------------------------------------------------------
__global__ __launch_bounds__(256) void fold_weights(
    const float* __restrict__ w_qk, const float* __restrict__ g_qk,
    const float* __restrict__ b_qk, const float* __restrict__ m_qk,
    const float* __restrict__ v_qk,
    const float* __restrict__ w_v, const float* __restrict__ g_v,
    const float* __restrict__ b_v, const float* __restrict__ m_v,
    const float* __restrict__ v_v,
    const float* __restrict__ w_p, const float* __restrict__ g_p,
    const float* __restrict__ b_p, const float* __restrict__ m_p,
    const float* __restrict__ v_p,
    unsigned short* __restrict__ wf1, float* __restrict__ shift1,
    unsigned short* __restrict__ wpf, float* __restrict__ shiftp)
{
    int row = blockIdx.x;
    int t   = threadIdx.x;
    if (row < 144) {
        float s, sh; const float* src;
        if (row < KDIM) {
            s  = g_qk[row] * rsqrtf(v_qk[row] + 1e-5f);
            sh = b_qk[row] - m_qk[row] * s;
            src = w_qk + row * CIN;
        } else {
            int o = row - KDIM;
            s  = g_v[o] * rsqrtf(v_v[o] + 1e-5f);
            sh = b_v[o] - m_v[o] * s;
            src = w_v + o * CIN;
        }
        wf1[row * CIN + t] = f2h(src[t] * s);
        if (t == 0) shift1[row] = sh;
    } else {
        int o = row - 144;
        float s = g_p[o] * rsqrtf(v_p[o] + 1e-5f);
        if (t < DHV) wpf[o * DHV + t] = f2h(w_p[o * DHV + t] * s);
        if (t == 0) shiftp[o] = b_p[o] - m_p[o] * s;
    }
}

// ---------------------------------------------------------------------------
// Kernel 1: projection GEMM (unchanged: x read exactly once).
// ---------------------------------------------------------------------------
__global__ __launch_bounds__(256) void proj_qkv(
    const float* __restrict__ x,
    const unsigned short* __restrict__ wf1, const float* __restrict__ shift1,
    unsigned short* __restrict__ qkT, unsigned short* __restrict__ Vt)
{
    const int b  = blockIdx.y;
    const int n0 = blockIdx.x * 64;
    const int tid  = threadIdx.x;
    const int w    = tid >> 6;
    const int lane = tid & 63;
    const int lg   = lane >> 4;
    const int lr   = lane & 15;
    const int n    = n0 + w * 16 + lr;

    const float* xb = x + (size_t)b * CIN * N_SP;
    f32x4 acc[9];
#pragma unroll
    for (int i = 0; i < 9; ++i) acc[i] = (f32x4){0.f, 0.f, 0.f, 0.f};

    for (int ks = 0; ks < 8; ++ks) {
        const int cbase = ks * 32 + lg * 8;
        ushort8 bx;
#pragma unroll
        for (int j = 0; j < 8; ++j) {
            float xv = xb[(size_t)(cbase + j) * N_SP + n];
            bx[j] = f2h(xv);
        }
#pragma unroll
        for (int ot = 0; ot < 9; ++ot) {
            ushort8 a = *(const ushort8*)(wf1 + (ot * 16 + lr) * CIN + cbase);
            acc[ot] = mfma16(a, bx, acc[ot]);
        }
    }

#pragma unroll
    for (int ot = 0; ot < 9; ++ot)
#pragma unroll
        for (int r = 0; r < 4; ++r) {
            int o = ot * 16 + lg * 4 + r;
            float val = acc[ot][r] + shift1[o];
            unsigned short hv = f2h(val);
            if (o < KDIM) qkT[((size_t)b * N_SP + n) * 32 + o] = hv;
            else          Vt[((size_t)b * DHV + (o - KDIM)) * N_SP + n] = hv;
        }

    // zero the K-padding columns 16..31 of qkT for this (b, n-tile)
    {
        int n_l  = tid >> 2;
        int part = tid & 3;
        unsigned long long* p = (unsigned long long*)
            (qkT + ((size_t)b * N_SP + n0 + n_l) * 32 + 16 + part * 4);
        *p = 0ULL;
    }
}

// ---------------------------------------------------------------------------
// Stage one 64-key tile (K 4KB + V 16KB) into LDS via global_load_lds,
// 20 x 1KB chunks; wave-quadrant wq issues chunks [wq*5, wq*5+5).
// Source pre-swizzled (rule 21):
//   K: lds[row][c4] = K[row][c4 ^ (row&3)]   (16B slots of 64B row)
//   V: lds[row][c8] = V[row][c8 ^ (row&7)]   (16B slots of 128B row)
// ---------------------------------------------------------------------------
__device__ __forceinline__ void stage_tile(
    const unsigned short* __restrict__ qk_b,
    const unsigned short* __restrict__ vt_b,
    unsigned short* k_l, unsigned short* v_l,
    int k0, int wq, int lane)
{
#pragma unroll
    for (int s = 0; s < 5; ++s) {
        const int idx = wq * 5 + s;
        if (idx < 4) {
            int row = idx * 16 + (lane >> 2);
            int c4  = (lane & 3) ^ ((lane >> 2) & 3);
            const unsigned short* src = qk_b + (size_t)(k0 + row) * 32 + c4 * 8;
            __builtin_amdgcn_global_load_lds(
                (const __attribute__((address_space(1))) void*)src,
                (__attribute__((address_space(3))) void*)(k_l + idx * 512),
                16, 0, 0);
        } else {
            int vi  = idx - 4;
            int row = vi * 8 + (lane >> 3);
            int c8  = (lane & 7) ^ (lane >> 3);      // (row&7) == lane>>3
            const unsigned short* src = vt_b + (size_t)row * N_SP + k0 + c8 * 8;
            __builtin_amdgcn_global_load_lds(
                (const __attribute__((address_space(1))) void*)src,
                (__attribute__((address_space(3))) void*)(v_l + vi * 512),
                16, 0, 0);
        }
    }
}

// ---------------------------------------------------------------------------
// Kernel 2: flash attention, 8 waves, in-block key-split x2.
// Grid (64, B), 512 thr.  Waves 0-3 (stream 0): q-subtiles, keys [0,2048);
// waves 4-7 (stream 1): same q, keys [2048,4096).  Per-stream double-buffered
// K/V in LDS.  Stream-1 publishes fp16 partials into v_lds[1][0] (dead after
// loop), stream-0 merges (exp-weighted) and stores.
// ---------------------------------------------------------------------------
__global__ __launch_bounds__(512) void attn_kernel(
    const unsigned short* __restrict__ qkT,
    const unsigned short* __restrict__ Vt,
    unsigned short* __restrict__ xx)
{
    const int b  = blockIdx.y;
    const int q0 = blockIdx.x * 64;
    const int tid  = threadIdx.x;
    const int ws   = tid >> 6;               // wave 0..7
    const int strm = ws >> 2;                // key-stream 0,1
    const int wq   = ws & 3;                 // q-subtile
    const int lane = tid & 63;
    const int lg   = lane >> 4;
    const int lr   = lane & 15;

    const unsigned short* qk_b = qkT + (size_t)b * N_SP * 32;
    const unsigned short* vt_b = Vt  + (size_t)b * DHV * N_SP;
    const int qrow  = q0 + wq * 16;
    const int kbase = strm * (N_SP / 2);

    const ushort8 aq = *(const ushort8*)(qk_b + (size_t)(qrow + lr) * 32 + lg * 8);

    f32x4 acc[8];
#pragma unroll
    for (int i = 0; i < 8; ++i) acc[i] = (f32x4){0.f, 0.f, 0.f, 0.f};
    float m_r[4] = {-__builtin_inff(), -__builtin_inff(),
                    -__builtin_inff(), -__builtin_inff()};
    float l_r[4] = {0.f, 0.f, 0.f, 0.f};     // per-lane partial sums (deferred)

    __shared__ __align__(16) unsigned short k_lds[2][2][64 * 32];   // 16 KB
    __shared__ __align__(16) unsigned short v_lds[2][2][128 * 64];  // 64 KB
    __shared__ __align__(16) unsigned short p_lds[8][16][72];       // 18 KB
    __shared__ float pm1[64], pl1[64];                              // 512 B

    const f32x4 zero4 = {0.f, 0.f, 0.f, 0.f};

    // prologue: stage tile 0 of own stream into buffer 0
    stage_tile(qk_b, vt_b, k_lds[strm][0], v_lds[strm][0], kbase, wq, lane);

    for (int t = 0; t < 32; ++t) {
        const int cur = t & 1;
        __syncthreads();   // drains vmcnt -> buf[cur] ready; prev reads done
        if (t < 31)
            stage_tile(qk_b, vt_b, k_lds[strm][cur ^ 1], v_lds[strm][cur ^ 1],
                       kbase + (t + 1) * 64, wq, lane);

        const unsigned short* kl = k_lds[strm][cur];
        const unsigned short* vl = v_lds[strm][cur];

        // ---- S = Q K^T for this wave's 16 queries x 64 keys (K from LDS) -
        f32x4 s[4];
#pragma unroll
        for (int tt = 0; tt < 4; ++tt) {
            int row = tt * 16 + lr;
            ushort8 bk = *(const ushort8*)(kl + row * 32 + ((lg ^ (lr & 3)) << 3));
            s[tt] = mfma16(aq, bk, zero4);
        }

        // ---- online softmax (rows = lg*4+r, max-reduce over lane&15) -----
        float sc_r[4];
#pragma unroll
        for (int r = 0; r < 4; ++r) {
            float mx = fmaxf(fmaxf(s[0][r], s[1][r]), fmaxf(s[2][r], s[3][r]));
            mx = fmaxf(mx, __shfl_xor(mx, 1));
            mx = fmaxf(mx, __shfl_xor(mx, 2));
            mx = fmaxf(mx, __shfl_xor(mx, 4));
            mx = fmaxf(mx, __shfl_xor(mx, 8));
            float mnew = fmaxf(m_r[r], mx);
            float sc = __expf(m_r[r] - mnew);     // first iter: exp(-inf)=0
            float rs = 0.f;
#pragma unroll
            for (int tt = 0; tt < 4; ++tt) {
                float p = __expf(s[tt][r] - mnew);
                s[tt][r] = p;
                rs += p;
            }
            l_r[r] = l_r[r] * sc + rs;            // deferred cross-lane sum
            m_r[r] = mnew;
            sc_r[r] = sc;
        }

        // ---- rescale accumulator ----------------------------------------
#pragma unroll
        for (int nn = 0; nn < 8; ++nn)
#pragma unroll
            for (int r = 0; r < 4; ++r) acc[nn][r] *= sc_r[r];

        // ---- P -> LDS transpose (own wave region, no barrier needed) -----
#pragma unroll
        for (int tt = 0; tt < 4; ++tt)
#pragma unroll
            for (int r = 0; r < 4; ++r)
                p_lds[ws][lg * 4 + r][tt * 16 + lr] = f2h(s[tt][r]);

        // ---- O += P @ V  (V from LDS, swizzled read) ---------------------
#pragma unroll
        for (int ks = 0; ks < 2; ++ks) {
            ushort8 pa = *(const ushort8*)(&p_lds[ws][lr][ks * 32 + lg * 8]);
#pragma unroll
            for (int nn = 0; nn < 8; ++nn) {
                int row = nn * 16 + lr;
                ushort8 vbf = *(const ushort8*)
                    (vl + row * 64 + ((((ks << 2) + lg) ^ (lr & 7)) << 3));
                acc[nn] = mfma16(pa, vbf, acc[nn]);
            }
        }
    }

    // ---- finish deferred l: reduce across lane&15 ------------------------
#pragma unroll
    for (int r = 0; r < 4; ++r) {
        float rs = l_r[r];
        rs += __shfl_xor(rs, 1);
        rs += __shfl_xor(rs, 2);
        rs += __shfl_xor(rs, 4);
        rs += __shfl_xor(rs, 8);
        l_r[r] = rs;
    }

    // ---- stream 1: publish fp16 partials into dead V-buffer --------------
    unsigned short* v_re = &v_lds[1][0][0];        // reused as [64][128] fp16
    if (strm == 1) {
#pragma unroll
        for (int r = 0; r < 4; ++r) {
            int rloc = wq * 16 + lg * 4 + r;
#pragma unroll
            for (int nn = 0; nn < 8; ++nn)
                v_re[rloc * 128 + nn * 16 + lr] = f2h(acc[nn][r]);
            if (lr == 0) { pm1[rloc] = m_r[r]; pl1[rloc] = l_r[r]; }
        }
    }
    __syncthreads();

    // ---- stream 0: exp-weighted merge, normalize, relu, store ------------
    if (strm == 0) {
        const size_t xoff = (size_t)b * N_SP * DHV;
#pragma unroll
        for (int r = 0; r < 4; ++r) {
            int rloc = wq * 16 + lg * 4 + r;
            float m1 = pm1[rloc], l1 = pl1[rloc];
            float M  = fmaxf(m_r[r], m1);
            float w0 = __expf(m_r[r] - M);
            float w1 = __expf(m1 - M);
            float L  = l_r[r] * w0 + l1 * w1;
            float inv = 1.0f / L;
            int q = q0 + rloc;
#pragma unroll
            for (int nn = 0; nn < 8; ++nn) {
                float o = acc[nn][r] * w0
                        + h2f(v_re[rloc * 128 + nn * 16 + lr]) * w1;
                xx[xoff + (size_t)q * DHV + nn * 16 + lr]
                    = f2h(fmaxf(o * inv, 0.f));
            }
        }
    }
}

// ---------------------------------------------------------------------------
// Kernel 3: output projection (unchanged).
// ---------------------------------------------------------------------------
__global__ __launch_bounds__(256) void proj_out(
    const unsigned short* __restrict__ xx,
    const unsigned short* __restrict__ wpf, const float* __restrict__ shiftp,
    float* __restrict__ out)
{
    const int b  = blockIdx.z;
    const int n0 = blockIdx.y * 64;
    const int o0 = blockIdx.x * 64 + (threadIdx.x >> 6) * 16;
    const int lane = threadIdx.x & 63;
    const int lg   = lane >> 4;
    const int lr   = lane & 15;

    f32x4 acc[4];
#pragma unroll
    for (int i = 0; i < 4; ++i) acc[i] = (f32x4){0.f, 0.f, 0.f, 0.f};

    const unsigned short* xb = xx + (size_t)b * N_SP * DHV;

    for (int ks = 0; ks < 4; ++ks) {
        ushort8 a = *(const ushort8*)(wpf + (size_t)(o0 + lr) * DHV + ks * 32 + lg * 8);
#pragma unroll
        for (int nt = 0; nt < 4; ++nt) {
            ushort8 bfr = *(const ushort8*)
                (xb + (size_t)(n0 + nt * 16 + lr) * DHV + ks * 32 + lg * 8);
            acc[nt] = mfma16(a, bfr, acc[nt]);
        }
    }

#pragma unroll
    for (int nt = 0; nt < 4; ++nt)
#pragma unroll
        for (int r = 0; r < 4; ++r) {
            int o = o0 + lg * 4 + r;
            out[((size_t)b * CIN + o) * N_SP + n0 + nt * 16 + lr]
                = acc[nt][r] + shiftp[o];
        }
}

// ---------------------------------------------------------------------------
extern "C" void kernel_launch(void* const* d_in, const int* in_sizes, int n_in,
                              void* d_out, int out_size, void* d_ws, size_t ws_size,
                              hipStream_t stream)
{
    const float* x    = (const float*)d_in[0];
    const float* w_qk = (const float*)d_in[2];
    const float* g_qk = (const float*)d_in[3];
    const float* b_qk = (const float*)d_in[4];
    const float* m_qk = (const float*)d_in[5];
    const float* v_qk = (const float*)d_in[6];
    const float* w_v  = (const float*)d_in[7];
    const float* g_v  = (const float*)d_in[8];
    const float* b_v  = (const float*)d_in[9];
    const float* m_v  = (const float*)d_in[10];
    const float* v_v  = (const float*)d_in[11];
    const float* w_p  = (const float*)d_in[12];
    const float* g_p  = (const float*)d_in[13];
    const float* b_p  = (const float*)d_in[14];
    const float* m_p  = (const float*)d_in[15];
    const float* v_p  = (const float*)d_in[16];

    char* ws = (char*)d_ws;
    unsigned short* qkT = (unsigned short*)(ws);                    // 1 MB
    unsigned short* Vt  = (unsigned short*)(ws + (1u << 20));       // 4 MB
    unsigned short* xxb = (unsigned short*)(ws + (5u << 20));       // 4 MB
    unsigned short* wf1 = (unsigned short*)(ws + (9u << 20));       // 72 KB
    float* shift1       = (float*)(ws + (9u << 20) + 80 * 1024);    // 576 B
    unsigned short* wpf = (unsigned short*)(ws + (9u << 20) + 84 * 1024); // 64 KB
    float* shiftp       = (float*)(ws + (9u << 20) + 148 * 1024);   // 1 KB

    fold_weights<<<400, 256, 0, stream>>>(
        w_qk, g_qk, b_qk, m_qk, v_qk,
        w_v, g_v, b_v, m_v, v_v,
        w_p, g_p, b_p, m_p, v_p,
        wf1, shift1, wpf, shiftp);

    proj_qkv<<<dim3(64, 4), 256, 0, stream>>>(x, wf1, shift1, qkT, Vt);

    attn_kernel<<<dim3(64, 4), 512, 0, stream>>>(qkT, Vt, xxb);

    proj_out<<<dim3(4, 64, 4), 256, 0, stream>>>(xxb, wpf, shiftp, (float*)d_out);
}

// Round 12
// 79.126 us; speedup vs baseline: 2.0854x; 1.2845x over previous
//
#include <hip/hip_runtime.h>
#include <cstdint>
#include <cstddef>

// ---------------------------------------------------------------------------
// Attention_Param_sharing_Kv_sharing: B=4, C=256, H=W=64 (N=4096), KD=16,
// NH=8, DH=128.  Gram-matrix attention, one shared KV head.
//
// R9 (verified, 101.6us total / 72.7 attn): 16x16 flash, LDS K/V staging.
// R10/R11: swapped 32x32x16 structure -> absmax 9.5e4 (fp16-saturation
//   signature).  Bounded-error analysis says layout errors can't do that;
//   prime suspects are the two unverified primitives: raw-asm
//   v_permlane32_swap (guessed semantics) and cvt_pkrtz return handling.
// R12: same structure, suspects replaced by documented primitives:
//   - fp16 pack via RNE casts + integer pack (no cvt_pkrtz)
//   - lane-pair exchange via __shfl(x, lane^32) (verified in R4-R9)
//   - always-rescale online softmax (no defer-max): P<=1, l<=1024
//   Everything else identical to R11 (V staging = R9-verified pattern).
// ---------------------------------------------------------------------------

typedef __attribute__((ext_vector_type(4)))  float f32x4;
typedef __attribute__((ext_vector_type(16))) float f32x16;
typedef __attribute__((ext_vector_type(8)))  _Float16 half8;
typedef __attribute__((ext_vector_type(8)))  unsigned short ushort8;
typedef __attribute__((ext_vector_type(2)))  unsigned u32x2;
typedef __attribute__((ext_vector_type(4)))  unsigned u32x4;

#define N_SP 4096
#define CIN  256
#define KDIM 16
#define DHV  128

__device__ __forceinline__ unsigned short f2h(float f) {
    _Float16 h = (_Float16)f;             // RNE
    return __builtin_bit_cast(unsigned short, h);
}
__device__ __forceinline__ float h2f(unsigned short u) {
    return (float)__builtin_bit_cast(_Float16, u);
}
__device__ __forceinline__ unsigned pk2(float a, float b) {
    return (unsigned)f2h(a) | ((unsigned)f2h(b) << 16);
}
__device__ __forceinline__ unsigned shfl32u(unsigned v, int src) {
    return (unsigned)__shfl((int)v, src, 64);
}
__device__ __forceinline__ f32x4 mfma16(ushort8 a, ushort8 b, f32x4 c) {
    return __builtin_amdgcn_mfma_f32_16x16x32_f16(
        __builtin_bit_cast(half8, a), __builtin_bit_cast(half8, b), c, 0, 0, 0);
}
__device__ __forceinline__ f32x16 mfma32(half8 a, half8 b, f32x16 c) {
    return __builtin_amdgcn_mfma_f32_32x32x16_f16(a, b, c, 0, 0, 0);
}

// ---------------------------------------------------------------------------
// Kernel 0: fold BN into weights (unchanged, verified).
// ---------------------------------------------------------------------------
__global__ __launch_bounds__(256) void fold_weights(
    const float* __restrict__ w_qk, const float* __restrict__ g_qk,
    const float* __restrict__ b_qk, const float* __restrict__ m_qk,
    const float* __restrict__ v_qk,
    const float* __restrict__ w_v, const float* __restrict__ g_v,
    const float* __restrict__ b_v, const float* __restrict__ m_v,
    const float* __restrict__ v_v,
    const float* __restrict__ w_p, const float* __restrict__ g_p,
    const float* __restrict__ b_p, const float* __restrict__ m_p,
    const float* __restrict__ v_p,
    unsigned short* __restrict__ wf1, float* __restrict__ shift1,
    unsigned short* __restrict__ wpf, float* __restrict__ shiftp)
{
    int row = blockIdx.x;
    int t   = threadIdx.x;
    if (row < 144) {
        float s, sh; const float* src;
        if (row < KDIM) {
            s  = g_qk[row] * rsqrtf(v_qk[row] + 1e-5f);
            sh = b_qk[row] - m_qk[row] * s;
            src = w_qk + row * CIN;
        } else {
            int o = row - KDIM;
            s  = g_v[o] * rsqrtf(v_v[o] + 1e-5f);
            sh = b_v[o] - m_v[o] * s;
            src = w_v + o * CIN;
        }
        wf1[row * CIN + t] = f2h(src[t] * s);
        if (t == 0) shift1[row] = sh;
    } else {
        int o = row - 144;
        float s = g_p[o] * rsqrtf(v_p[o] + 1e-5f);
        if (t < DHV) wpf[o * DHV + t] = f2h(w_p[o * DHV + t] * s);
        if (t == 0) shiftp[o] = b_p[o] - m_p[o] * s;
    }
}

// ---------------------------------------------------------------------------
// Kernel 1: projection GEMM (x read once).  qkT [b][n][16] f16 (no pad).
// ---------------------------------------------------------------------------
__global__ __launch_bounds__(256) void proj_qkv(
    const float* __restrict__ x,
    const unsigned short* __restrict__ wf1, const float* __restrict__ shift1,
    unsigned short* __restrict__ qkT, unsigned short* __restrict__ Vt)
{
    const int b  = blockIdx.y;
    const int n0 = blockIdx.x * 64;
    const int tid  = threadIdx.x;
    const int w    = tid >> 6;
    const int lane = tid & 63;
    const int lg   = lane >> 4;
    const int lr   = lane & 15;
    const int n    = n0 + w * 16 + lr;

    const float* xb = x + (size_t)b * CIN * N_SP;
    f32x4 acc[9];
#pragma unroll
    for (int i = 0; i < 9; ++i) acc[i] = (f32x4){0.f, 0.f, 0.f, 0.f};

    for (int ks = 0; ks < 8; ++ks) {
        const int cbase = ks * 32 + lg * 8;
        ushort8 bx;
#pragma unroll
        for (int j = 0; j < 8; ++j) {
            float xv = xb[(size_t)(cbase + j) * N_SP + n];
            bx[j] = f2h(xv);
        }
#pragma unroll
        for (int ot = 0; ot < 9; ++ot) {
            ushort8 a = *(const ushort8*)(wf1 + (ot * 16 + lr) * CIN + cbase);
            acc[ot] = mfma16(a, bx, acc[ot]);
        }
    }

#pragma unroll
    for (int ot = 0; ot < 9; ++ot)
#pragma unroll
        for (int r = 0; r < 4; ++r) {
            int o = ot * 16 + lg * 4 + r;
            float val = acc[ot][r] + shift1[o];
            unsigned short hv = f2h(val);
            if (o < KDIM) qkT[((size_t)b * N_SP + n) * 16 + o] = hv;
            else          Vt[((size_t)b * DHV + (o - KDIM)) * N_SP + n] = hv;
        }
}

// ---------------------------------------------------------------------------
// Stage one 64-key V tile (128 d x 64 halves = 16 KB) via global_load_lds,
// 16 x 1KB chunks; wave p of the stream issues chunks [p*8, p*8+8).
// Source pre-swizzled (rule 21, R8/R9-verified pattern): physical 16B slot
// s of row d holds logical slot s ^ (d&7).
// ---------------------------------------------------------------------------
__device__ __forceinline__ void stage_v(
    const unsigned short* __restrict__ vt_b,
    unsigned short* v_l, int k0, int p, int lane)
{
#pragma unroll
    for (int s = 0; s < 8; ++s) {
        const int vi = p * 8 + s;
        const int d  = vi * 8 + (lane >> 3);
        const int c8 = (lane & 7) ^ ((lane >> 3) & 7);
        const unsigned short* src = vt_b + (size_t)d * N_SP + k0 + c8 * 8;
        __builtin_amdgcn_global_load_lds(
            (const __attribute__((address_space(1))) void*)src,
            (__attribute__((address_space(3))) void*)(v_l + vi * 512),
            16, 0, 0);
    }
}

// V A-frag for PV: A[m=d][k]: lane&31 = d-row, k = (lane>>5)*8 + j.
__device__ __forceinline__ half8 ldv(const unsigned short* vl, int nb, int kc,
                                     int la31, int hi)
{
    const int d = nb * 32 + la31;
    const ushort8 v = *(const ushort8*)
        (vl + d * 64 + (((kc * 2 + hi) ^ (d & 7)) << 3));
    return __builtin_bit_cast(half8, v);
}

// ---------------------------------------------------------------------------
// Kernel 2: flash attention, swapped 32x32 structure.
// Grid (64, B), 512 thr = 8 waves = 4 streams x 2 waves.  Stream s: keys
// [s*1024,(s+1)*1024), wave p of stream: queries q0+p*32 .. +31.
// S = mfma32(A=K, B=Q): lane owns one query's scores -> in-lane softmax.
// P B-frag built via f2h-pack + __shfl(lane^32) exchange.
// PV = mfma32(A=V, B=P); merge via LDS reuse of V buffers.
// ---------------------------------------------------------------------------
__global__ __launch_bounds__(512, 2) void attn_kernel(
    const unsigned short* __restrict__ qkT,   // [b][n][16] f16
    const unsigned short* __restrict__ Vt,    // [b][128][n] f16
    unsigned short* __restrict__ xx)          // [b][n][128] f16
{
    const int b  = blockIdx.y;
    const int q0 = blockIdx.x * 64;
    const int tid  = threadIdx.x;
    const int ws   = tid >> 6;
    const int strm = ws >> 1;          // key-stream 0..3
    const int p    = ws & 1;           // q-half 0..1
    const int lane = tid & 63;
    const int la31 = lane & 31;
    const int hi   = lane >> 5;

    const unsigned short* qk_b = qkT + (size_t)b * N_SP * 16;
    const unsigned short* vt_b = Vt  + (size_t)b * DHV * N_SP;
    const int kbase = strm * (N_SP / 4);
    const int qrow  = q0 + p * 32;

    // Q B-frag (col n = query = lane&31, k = hi*8+j)
    const half8 aq = __builtin_bit_cast(half8,
        *(const ushort8*)(qk_b + (size_t)(qrow + la31) * 16 + hi * 8));

    f32x16 acc0, acc1, acc2, acc3, z16;
#pragma unroll
    for (int i = 0; i < 16; ++i) { z16[i] = 0.f; }
    acc0 = z16; acc1 = z16; acc2 = z16; acc3 = z16;
    float m_r = -__builtin_inff();
    float l_r = 0.f;

    __shared__ __align__(16) unsigned short v_lds[4][2][128 * 64];  // 128 KB
    __shared__ float lmbuf[4][64][2];                               // 2 KB

    stage_v(vt_b, &v_lds[strm][0][0], kbase, p, lane);

    for (int t = 0; t < 16; ++t) {
        const int cur = t & 1;
        __syncthreads();            // buf[cur] staged; prior reads drained
        if (t < 15)
            stage_v(vt_b, &v_lds[strm][cur ^ 1][0], kbase + (t + 1) * 64,
                    p, lane);
        const unsigned short* vl = &v_lds[strm][cur][0];
        const int k0 = kbase + t * 64;

        // ---- S = K Q^T: A = K rows (lane&31 = key), B = Q.  K from L2. ----
        const half8 kf0 = __builtin_bit_cast(half8,
            *(const ushort8*)(qk_b + (size_t)(k0 + la31) * 16 + hi * 8));
        const half8 kf1 = __builtin_bit_cast(half8,
            *(const ushort8*)(qk_b + (size_t)(k0 + 32 + la31) * 16 + hi * 8));
        f32x16 s0 = mfma32(kf0, aq, z16);     // keys k0..k0+31
        f32x16 s1 = mfma32(kf1, aq, z16);     // keys k0+32..k0+63

        // ---- in-lane softmax (lane pair l, l^32 shares query la31) --------
        float mpair[8];
#pragma unroll
        for (int i = 0; i < 8; ++i)
            mpair[i] = fmaxf(fmaxf(s0[i], s0[i + 8]), fmaxf(s1[i], s1[i + 8]));
        float mx = fmaxf(fmaxf(fmaxf(mpair[0], mpair[1]), fmaxf(mpair[2], mpair[3])),
                         fmaxf(fmaxf(mpair[4], mpair[5]), fmaxf(mpair[6], mpair[7])));
        mx = fmaxf(mx, __shfl(mx, lane ^ 32));   // other 32 keys on lane^32

        // always-rescale online softmax (P <= 1, l <= 1024: no fp16 risk)
        {
            float mnew = fmaxf(m_r, mx);          // mx finite -> mnew finite
            float sc = __expf(m_r - mnew);        // first tile: exp(-inf)=0
            l_r *= sc;
#pragma unroll
            for (int i = 0; i < 16; ++i) {
                acc0[i] *= sc; acc1[i] *= sc; acc2[i] *= sc; acc3[i] *= sc;
            }
            m_r = mnew;
        }
#pragma unroll
        for (int i = 0; i < 16; ++i) s0[i] = __expf(s0[i] - m_r);
#pragma unroll
        for (int i = 0; i < 16; ++i) s1[i] = __expf(s1[i] - m_r);
        float rpair[8];
#pragma unroll
        for (int i = 0; i < 8; ++i)
            rpair[i] = (s0[i] + s0[i + 8]) + (s1[i] + s1[i + 8]);
        l_r += ((rpair[0] + rpair[1]) + (rpair[2] + rpair[3]))
             + ((rpair[4] + rpair[5]) + (rpair[6] + rpair[7]));

        // ---- O += V^T P : A = V (m=d), B = P (n=query) --------------------
        // P B-frag per 16-key chunk.  Lane's s-elements map to keys
        // r(i) = (i&3) + 8*(i>>2) + 4*hi (D-layout, m74/m101-verified).
        // Exchange with lane^32 (same query) via __shfl:
        //   lo lane words = {a0, a1, partner a0, partner a1}
        //   hi lane words = {partner a2, partner a3, a2, a3}
#define PV_CHUNK(SV, B0, KC)                                               \
        {                                                                  \
            unsigned a0 = pk2(SV[B0 + 0], SV[B0 + 1]);                     \
            unsigned a1 = pk2(SV[B0 + 2], SV[B0 + 3]);                     \
            unsigned a2 = pk2(SV[B0 + 4], SV[B0 + 5]);                     \
            unsigned a3 = pk2(SV[B0 + 6], SV[B0 + 7]);                     \
            unsigned p0 = shfl32u(a0, lane ^ 32);                          \
            unsigned p1 = shfl32u(a1, lane ^ 32);                          \
            unsigned p2 = shfl32u(a2, lane ^ 32);                          \
            unsigned p3 = shfl32u(a3, lane ^ 32);                          \
            u32x4 pw;                                                      \
            pw.x = hi ? p2 : a0;                                           \
            pw.y = hi ? p3 : a1;                                           \
            pw.z = hi ? a2 : p0;                                           \
            pw.w = hi ? a3 : p1;                                           \
            half8 pb = __builtin_bit_cast(half8, pw);                      \
            acc0 = mfma32(ldv(vl, 0, KC, la31, hi), pb, acc0);             \
            acc1 = mfma32(ldv(vl, 1, KC, la31, hi), pb, acc1);             \
            acc2 = mfma32(ldv(vl, 2, KC, la31, hi), pb, acc2);             \
            acc3 = mfma32(ldv(vl, 3, KC, la31, hi), pb, acc3);             \
        }
        PV_CHUNK(s0, 0, 0)
        PV_CHUNK(s0, 8, 1)
        PV_CHUNK(s1, 0, 2)
        PV_CHUNK(s1, 8, 3)
#undef PV_CHUNK
    }

    // ---- finish l: other half of the keys lives on lane^32 ---------------
    l_r = l_r + __shfl(l_r, lane ^ 32);

    __syncthreads();   // all streams done reading V bufs -> safe to reuse

    // ---- publish normalized partial O (fp16) + (m,l) ---------------------
    // Opart reuses v_lds[0..1]: [4 streams][64 q][128 d] halves = 64 KB.
    unsigned short* Opart = &v_lds[0][0][0];
    const int qib = p * 32 + la31;            // q within block
    if (hi == 0) {
        lmbuf[strm][qib][0] = m_r;
        lmbuf[strm][qib][1] = l_r;
    }
    {
        const float invl = 1.0f / l_r;        // own-lane query; l_r >= 1
        const size_t qoff = ((size_t)strm * 64 + qib) * 128;
        // acc reg rq*4+j covers d = NB*32 + 8*rq + 4*hi + j (j=0..3)
#define PUB(ACC, NB)                                                       \
        {                                                                  \
            _Pragma("unroll")                                              \
            for (int rq = 0; rq < 4; ++rq) {                               \
                float v0 = ACC[rq * 4 + 0] * invl;                         \
                float v1 = ACC[rq * 4 + 1] * invl;                         \
                float v2 = ACC[rq * 4 + 2] * invl;                         \
                float v3 = ACC[rq * 4 + 3] * invl;                         \
                u32x2 wv; wv.x = pk2(v0, v1); wv.y = pk2(v2, v3);          \
                *(u32x2*)(Opart + qoff + NB * 32 + rq * 8 + 4 * hi) = wv;  \
            }                                                              \
        }
        PUB(acc0, 0) PUB(acc1, 1) PUB(acc2, 2) PUB(acc3, 3)
#undef PUB
    }
    __syncthreads();

    // ---- merge 4 streams: thread t -> q = t>>3, d-seg = (t&7)*16 ---------
    {
        const int q    = tid >> 3;
        const int dseg = (tid & 7) * 16;
        const float m0 = lmbuf[0][q][0], l0 = lmbuf[0][q][1];
        const float m1 = lmbuf[1][q][0], l1 = lmbuf[1][q][1];
        const float m2 = lmbuf[2][q][0], l2 = lmbuf[2][q][1];
        const float m3 = lmbuf[3][q][0], l3 = lmbuf[3][q][1];
        const float M = fmaxf(fmaxf(m0, m1), fmaxf(m2, m3));
        float w0 = l0 * __expf(m0 - M);
        float w1 = l1 * __expf(m1 - M);
        float w2 = l2 * __expf(m2 - M);
        float w3 = l3 * __expf(m3 - M);
        const float inv = 1.0f / (w0 + w1 + w2 + w3);   // >= 1 term with w>=1
        w0 *= inv; w1 *= inv; w2 *= inv; w3 *= inv;

        const ushort8 A0 = *(const ushort8*)(Opart + (0 * 64 + q) * 128 + dseg);
        const ushort8 A1 = *(const ushort8*)(Opart + (1 * 64 + q) * 128 + dseg);
        const ushort8 A2 = *(const ushort8*)(Opart + (2 * 64 + q) * 128 + dseg);
        const ushort8 A3 = *(const ushort8*)(Opart + (3 * 64 + q) * 128 + dseg);
        const ushort8 B0 = *(const ushort8*)(Opart + (0 * 64 + q) * 128 + dseg + 8);
        const ushort8 B1 = *(const ushort8*)(Opart + (1 * 64 + q) * 128 + dseg + 8);
        const ushort8 B2 = *(const ushort8*)(Opart + (2 * 64 + q) * 128 + dseg + 8);
        const ushort8 B3 = *(const ushort8*)(Opart + (3 * 64 + q) * 128 + dseg + 8);

        ushort8 o0, o1;
#pragma unroll
        for (int i = 0; i < 8; ++i) {
            float va = w0 * h2f(A0[i]) + w1 * h2f(A1[i])
                     + w2 * h2f(A2[i]) + w3 * h2f(A3[i]);
            float vb = w0 * h2f(B0[i]) + w1 * h2f(B1[i])
                     + w2 * h2f(B2[i]) + w3 * h2f(B3[i]);
            o0[i] = f2h(fmaxf(va, 0.f));
            o1[i] = f2h(fmaxf(vb, 0.f));
        }
        const size_t xo = ((size_t)b * N_SP + q0 + q) * 128 + dseg;
        *(ushort8*)(xx + xo)     = o0;
        *(ushort8*)(xx + xo + 8) = o1;
    }
}

// ---------------------------------------------------------------------------
// Kernel 3: output projection (unchanged, verified).
// ---------------------------------------------------------------------------
__global__ __launch_bounds__(256) void proj_out(
    const unsigned short* __restrict__ xx,
    const unsigned short* __restrict__ wpf, const float* __restrict__ shiftp,
    float* __restrict__ out)
{
    const int b  = blockIdx.z;
    const int n0 = blockIdx.y * 64;
    const int o0 = blockIdx.x * 64 + (threadIdx.x >> 6) * 16;
    const int lane = threadIdx.x & 63;
    const int lg   = lane >> 4;
    const int lr   = lane & 15;

    f32x4 acc[4];
#pragma unroll
    for (int i = 0; i < 4; ++i) acc[i] = (f32x4){0.f, 0.f, 0.f, 0.f};

    const unsigned short* xb = xx + (size_t)b * N_SP * DHV;

    for (int ks = 0; ks < 4; ++ks) {
        ushort8 a = *(const ushort8*)(wpf + (size_t)(o0 + lr) * DHV + ks * 32 + lg * 8);
#pragma unroll
        for (int nt = 0; nt < 4; ++nt) {
            ushort8 bfr = *(const ushort8*)
                (xb + (size_t)(n0 + nt * 16 + lr) * DHV + ks * 32 + lg * 8);
            acc[nt] = mfma16(a, bfr, acc[nt]);
        }
    }

#pragma unroll
    for (int nt = 0; nt < 4; ++nt)
#pragma unroll
        for (int r = 0; r < 4; ++r) {
            int o = o0 + lg * 4 + r;
            out[((size_t)b * CIN + o) * N_SP + n0 + nt * 16 + lr]
                = acc[nt][r] + shiftp[o];
        }
}

// ---------------------------------------------------------------------------
extern "C" void kernel_launch(void* const* d_in, const int* in_sizes, int n_in,
                              void* d_out, int out_size, void* d_ws, size_t ws_size,
                              hipStream_t stream)
{
    const float* x    = (const float*)d_in[0];
    const float* w_qk = (const float*)d_in[2];
    const float* g_qk = (const float*)d_in[3];
    const float* b_qk = (const float*)d_in[4];
    const float* m_qk = (const float*)d_in[5];
    const float* v_qk = (const float*)d_in[6];
    const float* w_v  = (const float*)d_in[7];
    const float* g_v  = (const float*)d_in[8];
    const float* b_v  = (const float*)d_in[9];
    const float* m_v  = (const float*)d_in[10];
    const float* v_v  = (const float*)d_in[11];
    const float* w_p  = (const float*)d_in[12];
    const float* g_p  = (const float*)d_in[13];
    const float* b_p  = (const float*)d_in[14];
    const float* m_p  = (const float*)d_in[15];
    const float* v_p  = (const float*)d_in[16];

    char* ws = (char*)d_ws;
    unsigned short* qkT = (unsigned short*)(ws);                    // 512 KB
    unsigned short* Vt  = (unsigned short*)(ws + (1u << 20));       // 4 MB
    unsigned short* xxb = (unsigned short*)(ws + (5u << 20));       // 4 MB
    unsigned short* wf1 = (unsigned short*)(ws + (9u << 20));       // 72 KB
    float* shift1       = (float*)(ws + (9u << 20) + 80 * 1024);    // 576 B
    unsigned short* wpf = (unsigned short*)(ws + (9u << 20) + 84 * 1024); // 64 KB
    float* shiftp       = (float*)(ws + (9u << 20) + 148 * 1024);   // 1 KB

    fold_weights<<<400, 256, 0, stream>>>(
        w_qk, g_qk, b_qk, m_qk, v_qk,
        w_v, g_v, b_v, m_v, v_v,
        w_p, g_p, b_p, m_p, v_p,
        wf1, shift1, wpf, shiftp);

    proj_qkv<<<dim3(64, 4), 256, 0, stream>>>(x, wf1, shift1, qkT, Vt);

    attn_kernel<<<dim3(64, 4), 512, 0, stream>>>(qkT, Vt, xxb);

    proj_out<<<dim3(4, 64, 4), 256, 0, stream>>>(xxb, wpf, shiftp, (float*)d_out);
}

// Round 13
// 71.986 us; speedup vs baseline: 2.2923x; 1.0992x over previous
//
#include <hip/hip_runtime.h>
#include <cstdint>
#include <cstddef>

// ---------------------------------------------------------------------------
// Attention_Param_sharing_Kv_sharing: B=4, C=256, H=W=64 (N=4096), KD=16,
// NH=8, DH=128.  Gram-matrix attention, one shared KV head.
//
// R12 (verified, 79.1us total / 49.7 attn): swapped 32x32x16 flash --
//   in-lane softmax, P in registers via f2h-pack + shfl(lane^32),
//   PV = mfma32(A=V,B=P), V staged via global_load_lds (pre-swizzled).
// R13 = R12 + two isolated low-risk cuts on the serial chain:
//   (1) K-fragment register prefetch (tile t+1's kf loaded during tile t;
//       was a fresh L2 load right before its MFMA = 200-400 cyc exposed).
//   (2) defer-max THR=8 (T13): skip the 65-op acc rescale when the tile
//       max doesn't grow; P<=e^8 fp16-safe, l<=3e6 fp32-safe.
// ---------------------------------------------------------------------------

typedef __attribute__((ext_vector_type(4)))  float f32x4;
typedef __attribute__((ext_vector_type(16))) float f32x16;
typedef __attribute__((ext_vector_type(8)))  _Float16 half8;
typedef __attribute__((ext_vector_type(8)))  unsigned short ushort8;
typedef __attribute__((ext_vector_type(2)))  unsigned u32x2;
typedef __attribute__((ext_vector_type(4)))  unsigned u32x4;

#define N_SP 4096
#define CIN  256
#define KDIM 16
#define DHV  128

__device__ __forceinline__ unsigned short f2h(float f) {
    _Float16 h = (_Float16)f;             // RNE
    return __builtin_bit_cast(unsigned short, h);
}
__device__ __forceinline__ float h2f(unsigned short u) {
    return (float)__builtin_bit_cast(_Float16, u);
}
__device__ __forceinline__ unsigned pk2(float a, float b) {
    return (unsigned)f2h(a) | ((unsigned)f2h(b) << 16);
}
__device__ __forceinline__ unsigned shfl32u(unsigned v, int src) {
    return (unsigned)__shfl((int)v, src, 64);
}
__device__ __forceinline__ f32x4 mfma16(ushort8 a, ushort8 b, f32x4 c) {
    return __builtin_amdgcn_mfma_f32_16x16x32_f16(
        __builtin_bit_cast(half8, a), __builtin_bit_cast(half8, b), c, 0, 0, 0);
}
__device__ __forceinline__ f32x16 mfma32(half8 a, half8 b, f32x16 c) {
    return __builtin_amdgcn_mfma_f32_32x32x16_f16(a, b, c, 0, 0, 0);
}

// ---------------------------------------------------------------------------
// Kernel 0: fold BN into weights (unchanged, verified).
// ---------------------------------------------------------------------------
__global__ __launch_bounds__(256) void fold_weights(
    const float* __restrict__ w_qk, const float* __restrict__ g_qk,
    const float* __restrict__ b_qk, const float* __restrict__ m_qk,
    const float* __restrict__ v_qk,
    const float* __restrict__ w_v, const float* __restrict__ g_v,
    const float* __restrict__ b_v, const float* __restrict__ m_v,
    const float* __restrict__ v_v,
    const float* __restrict__ w_p, const float* __restrict__ g_p,
    const float* __restrict__ b_p, const float* __restrict__ m_p,
    const float* __restrict__ v_p,
    unsigned short* __restrict__ wf1, float* __restrict__ shift1,
    unsigned short* __restrict__ wpf, float* __restrict__ shiftp)
{
    int row = blockIdx.x;
    int t   = threadIdx.x;
    if (row < 144) {
        float s, sh; const float* src;
        if (row < KDIM) {
            s  = g_qk[row] * rsqrtf(v_qk[row] + 1e-5f);
            sh = b_qk[row] - m_qk[row] * s;
            src = w_qk + row * CIN;
        } else {
            int o = row - KDIM;
            s  = g_v[o] * rsqrtf(v_v[o] + 1e-5f);
            sh = b_v[o] - m_v[o] * s;
            src = w_v + o * CIN;
        }
        wf1[row * CIN + t] = f2h(src[t] * s);
        if (t == 0) shift1[row] = sh;
    } else {
        int o = row - 144;
        float s = g_p[o] * rsqrtf(v_p[o] + 1e-5f);
        if (t < DHV) wpf[o * DHV + t] = f2h(w_p[o * DHV + t] * s);
        if (t == 0) shiftp[o] = b_p[o] - m_p[o] * s;
    }
}

// ---------------------------------------------------------------------------
// Kernel 1: projection GEMM (x read once).  qkT [b][n][16] f16 (no pad).
// ---------------------------------------------------------------------------
__global__ __launch_bounds__(256) void proj_qkv(
    const float* __restrict__ x,
    const unsigned short* __restrict__ wf1, const float* __restrict__ shift1,
    unsigned short* __restrict__ qkT, unsigned short* __restrict__ Vt)
{
    const int b  = blockIdx.y;
    const int n0 = blockIdx.x * 64;
    const int tid  = threadIdx.x;
    const int w    = tid >> 6;
    const int lane = tid & 63;
    const int lg   = lane >> 4;
    const int lr   = lane & 15;
    const int n    = n0 + w * 16 + lr;

    const float* xb = x + (size_t)b * CIN * N_SP;
    f32x4 acc[9];
#pragma unroll
    for (int i = 0; i < 9; ++i) acc[i] = (f32x4){0.f, 0.f, 0.f, 0.f};

    for (int ks = 0; ks < 8; ++ks) {
        const int cbase = ks * 32 + lg * 8;
        ushort8 bx;
#pragma unroll
        for (int j = 0; j < 8; ++j) {
            float xv = xb[(size_t)(cbase + j) * N_SP + n];
            bx[j] = f2h(xv);
        }
#pragma unroll
        for (int ot = 0; ot < 9; ++ot) {
            ushort8 a = *(const ushort8*)(wf1 + (ot * 16 + lr) * CIN + cbase);
            acc[ot] = mfma16(a, bx, acc[ot]);
        }
    }

#pragma unroll
    for (int ot = 0; ot < 9; ++ot)
#pragma unroll
        for (int r = 0; r < 4; ++r) {
            int o = ot * 16 + lg * 4 + r;
            float val = acc[ot][r] + shift1[o];
            unsigned short hv = f2h(val);
            if (o < KDIM) qkT[((size_t)b * N_SP + n) * 16 + o] = hv;
            else          Vt[((size_t)b * DHV + (o - KDIM)) * N_SP + n] = hv;
        }
}

// ---------------------------------------------------------------------------
// Stage one 64-key V tile (128 d x 64 halves = 16 KB) via global_load_lds,
// 16 x 1KB chunks; wave p of the stream issues chunks [p*8, p*8+8).
// Source pre-swizzled (rule 21): physical 16B slot s of row d holds
// logical slot s ^ (d&7).
// ---------------------------------------------------------------------------
__device__ __forceinline__ void stage_v(
    const unsigned short* __restrict__ vt_b,
    unsigned short* v_l, int k0, int p, int lane)
{
#pragma unroll
    for (int s = 0; s < 8; ++s) {
        const int vi = p * 8 + s;
        const int d  = vi * 8 + (lane >> 3);
        const int c8 = (lane & 7) ^ ((lane >> 3) & 7);
        const unsigned short* src = vt_b + (size_t)d * N_SP + k0 + c8 * 8;
        __builtin_amdgcn_global_load_lds(
            (const __attribute__((address_space(1))) void*)src,
            (__attribute__((address_space(3))) void*)(v_l + vi * 512),
            16, 0, 0);
    }
}

// V A-frag for PV: A[m=d][k]: lane&31 = d-row, k = (lane>>5)*8 + j.
__device__ __forceinline__ half8 ldv(const unsigned short* vl, int nb, int kc,
                                     int la31, int hi)
{
    const int d = nb * 32 + la31;
    const ushort8 v = *(const ushort8*)
        (vl + d * 64 + (((kc * 2 + hi) ^ (d & 7)) << 3));
    return __builtin_bit_cast(half8, v);
}

// K A-frag for S: A[m=key][k]: lane&31 = key-row, k = (lane>>5)*8 + j.
__device__ __forceinline__ half8 ldk(const unsigned short* qk_b, int krow,
                                     int la31, int hi)
{
    return __builtin_bit_cast(half8,
        *(const ushort8*)(qk_b + (size_t)(krow + la31) * 16 + hi * 8));
}

// ---------------------------------------------------------------------------
// Kernel 2: flash attention, swapped 32x32 structure.
// Grid (64, B), 512 thr = 8 waves = 4 streams x 2 waves.  Stream s: keys
// [s*1024,(s+1)*1024), wave p of stream: queries q0+p*32 .. +31.
// S = mfma32(A=K, B=Q): lane owns one query's scores -> in-lane softmax.
// K-frags register-prefetched one tile ahead; defer-max THR=8.
// ---------------------------------------------------------------------------
__global__ __launch_bounds__(512, 2) void attn_kernel(
    const unsigned short* __restrict__ qkT,   // [b][n][16] f16
    const unsigned short* __restrict__ Vt,    // [b][128][n] f16
    unsigned short* __restrict__ xx)          // [b][n][128] f16
{
    const int b  = blockIdx.y;
    const int q0 = blockIdx.x * 64;
    const int tid  = threadIdx.x;
    const int ws   = tid >> 6;
    const int strm = ws >> 1;          // key-stream 0..3
    const int p    = ws & 1;           // q-half 0..1
    const int lane = tid & 63;
    const int la31 = lane & 31;
    const int hi   = lane >> 5;

    const unsigned short* qk_b = qkT + (size_t)b * N_SP * 16;
    const unsigned short* vt_b = Vt  + (size_t)b * DHV * N_SP;
    const int kbase = strm * (N_SP / 4);
    const int qrow  = q0 + p * 32;

    // Q B-frag (col n = query = lane&31, k = hi*8+j)
    const half8 aq = __builtin_bit_cast(half8,
        *(const ushort8*)(qk_b + (size_t)(qrow + la31) * 16 + hi * 8));

    f32x16 acc0, acc1, acc2, acc3, z16;
#pragma unroll
    for (int i = 0; i < 16; ++i) { z16[i] = 0.f; }
    acc0 = z16; acc1 = z16; acc2 = z16; acc3 = z16;
    float m_r = -__builtin_inff();
    float l_r = 0.f;

    __shared__ __align__(16) unsigned short v_lds[4][2][128 * 64];  // 128 KB
    __shared__ float lmbuf[4][64][2];                               // 2 KB

    stage_v(vt_b, &v_lds[strm][0][0], kbase, p, lane);
    // K register prefetch for tile 0
    half8 kf0n = ldk(qk_b, kbase, la31, hi);
    half8 kf1n = ldk(qk_b, kbase + 32, la31, hi);

    for (int t = 0; t < 16; ++t) {
        const int cur = t & 1;
        __syncthreads();            // buf[cur] + kf*n ready; prior reads done
        if (t < 15)
            stage_v(vt_b, &v_lds[strm][cur ^ 1][0], kbase + (t + 1) * 64,
                    p, lane);
        const half8 kf0 = kf0n;
        const half8 kf1 = kf1n;
        if (t < 15) {               // prefetch K for tile t+1 (full-tile window)
            kf0n = ldk(qk_b, kbase + (t + 1) * 64, la31, hi);
            kf1n = ldk(qk_b, kbase + (t + 1) * 64 + 32, la31, hi);
        }
        const unsigned short* vl = &v_lds[strm][cur][0];

        // ---- S = K Q^T: A = K rows (lane&31 = key), B = Q -----------------
        f32x16 s0 = mfma32(kf0, aq, z16);     // keys k0..k0+31
        f32x16 s1 = mfma32(kf1, aq, z16);     // keys k0+32..k0+63

        // ---- in-lane softmax (lane pair l, l^32 shares query la31) --------
        float mpair[8];
#pragma unroll
        for (int i = 0; i < 8; ++i)
            mpair[i] = fmaxf(fmaxf(s0[i], s0[i + 8]), fmaxf(s1[i], s1[i + 8]));
        float mx = fmaxf(fmaxf(fmaxf(mpair[0], mpair[1]), fmaxf(mpair[2], mpair[3])),
                         fmaxf(fmaxf(mpair[4], mpair[5]), fmaxf(mpair[6], mpair[7])));
        mx = fmaxf(mx, __shfl(mx, lane ^ 32));   // other 32 keys on lane^32

        // defer-max (T13): rescale only when max grows past THR=8.
        // P <= e^8 = 2981 (fp16-safe), l <= 16*64*2981 ~ 3e6 (fp32-safe).
        if (!__all(mx <= m_r + 8.0f)) {
            float mnew = fmaxf(m_r, mx);          // first tile: -inf -> mx
            float sc = __expf(m_r - mnew);        // first tile: exp(-inf)=0
            l_r *= sc;
#pragma unroll
            for (int i = 0; i < 16; ++i) {
                acc0[i] *= sc; acc1[i] *= sc; acc2[i] *= sc; acc3[i] *= sc;
            }
            m_r = mnew;
        }
#pragma unroll
        for (int i = 0; i < 16; ++i) s0[i] = __expf(s0[i] - m_r);
#pragma unroll
        for (int i = 0; i < 16; ++i) s1[i] = __expf(s1[i] - m_r);
        float rpair[8];
#pragma unroll
        for (int i = 0; i < 8; ++i)
            rpair[i] = (s0[i] + s0[i + 8]) + (s1[i] + s1[i + 8]);
        l_r += ((rpair[0] + rpair[1]) + (rpair[2] + rpair[3]))
             + ((rpair[4] + rpair[5]) + (rpair[6] + rpair[7]));

        // ---- O += V^T P : A = V (m=d), B = P (n=query) --------------------
        // P B-frag per 16-key chunk; exchange with lane^32 via __shfl.
#define PV_CHUNK(SV, B0, KC)                                               \
        {                                                                  \
            unsigned a0 = pk2(SV[B0 + 0], SV[B0 + 1]);                     \
            unsigned a1 = pk2(SV[B0 + 2], SV[B0 + 3]);                     \
            unsigned a2 = pk2(SV[B0 + 4], SV[B0 + 5]);                     \
            unsigned a3 = pk2(SV[B0 + 6], SV[B0 + 7]);                     \
            unsigned p0 = shfl32u(a0, lane ^ 32);                          \
            unsigned p1 = shfl32u(a1, lane ^ 32);                          \
            unsigned p2 = shfl32u(a2, lane ^ 32);                          \
            unsigned p3 = shfl32u(a3, lane ^ 32);                          \
            u32x4 pw;                                                      \
            pw.x = hi ? p2 : a0;                                           \
            pw.y = hi ? p3 : a1;                                           \
            pw.z = hi ? a2 : p0;                                           \
            pw.w = hi ? a3 : p1;                                           \
            half8 pb = __builtin_bit_cast(half8, pw);                      \
            acc0 = mfma32(ldv(vl, 0, KC, la31, hi), pb, acc0);             \
            acc1 = mfma32(ldv(vl, 1, KC, la31, hi), pb, acc1);             \
            acc2 = mfma32(ldv(vl, 2, KC, la31, hi), pb, acc2);             \
            acc3 = mfma32(ldv(vl, 3, KC, la31, hi), pb, acc3);             \
        }
        PV_CHUNK(s0, 0, 0)
        PV_CHUNK(s0, 8, 1)
        PV_CHUNK(s1, 0, 2)
        PV_CHUNK(s1, 8, 3)
#undef PV_CHUNK
    }

    // ---- finish l: other half of the keys lives on lane^32 ---------------
    l_r = l_r + __shfl(l_r, lane ^ 32);

    __syncthreads();   // all streams done reading V bufs -> safe to reuse

    // ---- publish normalized partial O (fp16) + (m,l) ---------------------
    unsigned short* Opart = &v_lds[0][0][0];  // [4 streams][64 q][128 d] f16
    const int qib = p * 32 + la31;
    if (hi == 0) {
        lmbuf[strm][qib][0] = m_r;
        lmbuf[strm][qib][1] = l_r;
    }
    {
        const float invl = 1.0f / l_r;
        const size_t qoff = ((size_t)strm * 64 + qib) * 128;
#define PUB(ACC, NB)                                                       \
        {                                                                  \
            _Pragma("unroll")                                              \
            for (int rq = 0; rq < 4; ++rq) {                               \
                float v0 = ACC[rq * 4 + 0] * invl;                         \
                float v1 = ACC[rq * 4 + 1] * invl;                         \
                float v2 = ACC[rq * 4 + 2] * invl;                         \
                float v3 = ACC[rq * 4 + 3] * invl;                         \
                u32x2 wv; wv.x = pk2(v0, v1); wv.y = pk2(v2, v3);          \
                *(u32x2*)(Opart + qoff + NB * 32 + rq * 8 + 4 * hi) = wv;  \
            }                                                              \
        }
        PUB(acc0, 0) PUB(acc1, 1) PUB(acc2, 2) PUB(acc3, 3)
#undef PUB
    }
    __syncthreads();

    // ---- merge 4 streams: thread t -> q = t>>3, d-seg = (t&7)*16 ---------
    {
        const int q    = tid >> 3;
        const int dseg = (tid & 7) * 16;
        const float m0 = lmbuf[0][q][0], l0 = lmbuf[0][q][1];
        const float m1 = lmbuf[1][q][0], l1 = lmbuf[1][q][1];
        const float m2 = lmbuf[2][q][0], l2 = lmbuf[2][q][1];
        const float m3 = lmbuf[3][q][0], l3 = lmbuf[3][q][1];
        const float M = fmaxf(fmaxf(m0, m1), fmaxf(m2, m3));
        float w0 = l0 * __expf(m0 - M);
        float w1 = l1 * __expf(m1 - M);
        float w2 = l2 * __expf(m2 - M);
        float w3 = l3 * __expf(m3 - M);
        const float inv = 1.0f / (w0 + w1 + w2 + w3);
        w0 *= inv; w1 *= inv; w2 *= inv; w3 *= inv;

        const ushort8 A0 = *(const ushort8*)(Opart + (0 * 64 + q) * 128 + dseg);
        const ushort8 A1 = *(const ushort8*)(Opart + (1 * 64 + q) * 128 + dseg);
        const ushort8 A2 = *(const ushort8*)(Opart + (2 * 64 + q) * 128 + dseg);
        const ushort8 A3 = *(const ushort8*)(Opart + (3 * 64 + q) * 128 + dseg);
        const ushort8 B0 = *(const ushort8*)(Opart + (0 * 64 + q) * 128 + dseg + 8);
        const ushort8 B1 = *(const ushort8*)(Opart + (1 * 64 + q) * 128 + dseg + 8);
        const ushort8 B2 = *(const ushort8*)(Opart + (2 * 64 + q) * 128 + dseg + 8);
        const ushort8 B3 = *(const ushort8*)(Opart + (3 * 64 + q) * 128 + dseg + 8);

        ushort8 o0, o1;
#pragma unroll
        for (int i = 0; i < 8; ++i) {
            float va = w0 * h2f(A0[i]) + w1 * h2f(A1[i])
                     + w2 * h2f(A2[i]) + w3 * h2f(A3[i]);
            float vb = w0 * h2f(B0[i]) + w1 * h2f(B1[i])
                     + w2 * h2f(B2[i]) + w3 * h2f(B3[i]);
            o0[i] = f2h(fmaxf(va, 0.f));
            o1[i] = f2h(fmaxf(vb, 0.f));
        }
        const size_t xo = ((size_t)b * N_SP + q0 + q) * 128 + dseg;
        *(ushort8*)(xx + xo)     = o0;
        *(ushort8*)(xx + xo + 8) = o1;
    }
}

// ---------------------------------------------------------------------------
// Kernel 3: output projection (unchanged, verified).
// ---------------------------------------------------------------------------
__global__ __launch_bounds__(256) void proj_out(
    const unsigned short* __restrict__ xx,
    const unsigned short* __restrict__ wpf, const float* __restrict__ shiftp,
    float* __restrict__ out)
{
    const int b  = blockIdx.z;
    const int n0 = blockIdx.y * 64;
    const int o0 = blockIdx.x * 64 + (threadIdx.x >> 6) * 16;
    const int lane = threadIdx.x & 63;
    const int lg   = lane >> 4;
    const int lr   = lane & 15;

    f32x4 acc[4];
#pragma unroll
    for (int i = 0; i < 4; ++i) acc[i] = (f32x4){0.f, 0.f, 0.f, 0.f};

    const unsigned short* xb = xx + (size_t)b * N_SP * DHV;

    for (int ks = 0; ks < 4; ++ks) {
        ushort8 a = *(const ushort8*)(wpf + (size_t)(o0 + lr) * DHV + ks * 32 + lg * 8);
#pragma unroll
        for (int nt = 0; nt < 4; ++nt) {
            ushort8 bfr = *(const ushort8*)
                (xb + (size_t)(n0 + nt * 16 + lr) * DHV + ks * 32 + lg * 8);
            acc[nt] = mfma16(a, bfr, acc[nt]);
        }
    }

#pragma unroll
    for (int nt = 0; nt < 4; ++nt)
#pragma unroll
        for (int r = 0; r < 4; ++r) {
            int o = o0 + lg * 4 + r;
            out[((size_t)b * CIN + o) * N_SP + n0 + nt * 16 + lr]
                = acc[nt][r] + shiftp[o];
        }
}

// ---------------------------------------------------------------------------
extern "C" void kernel_launch(void* const* d_in, const int* in_sizes, int n_in,
                              void* d_out, int out_size, void* d_ws, size_t ws_size,
                              hipStream_t stream)
{
    const float* x    = (const float*)d_in[0];
    const float* w_qk = (const float*)d_in[2];
    const float* g_qk = (const float*)d_in[3];
    const float* b_qk = (const float*)d_in[4];
    const float* m_qk = (const float*)d_in[5];
    const float* v_qk = (const float*)d_in[6];
    const float* w_v  = (const float*)d_in[7];
    const float* g_v  = (const float*)d_in[8];
    const float* b_v  = (const float*)d_in[9];
    const float* m_v  = (const float*)d_in[10];
    const float* v_v  = (const float*)d_in[11];
    const float* w_p  = (const float*)d_in[12];
    const float* g_p  = (const float*)d_in[13];
    const float* b_p  = (const float*)d_in[14];
    const float* m_p  = (const float*)d_in[15];
    const float* v_p  = (const float*)d_in[16];

    char* ws = (char*)d_ws;
    unsigned short* qkT = (unsigned short*)(ws);                    // 512 KB
    unsigned short* Vt  = (unsigned short*)(ws + (1u << 20));       // 4 MB
    unsigned short* xxb = (unsigned short*)(ws + (5u << 20));       // 4 MB
    unsigned short* wf1 = (unsigned short*)(ws + (9u << 20));       // 72 KB
    float* shift1       = (float*)(ws + (9u << 20) + 80 * 1024);    // 576 B
    unsigned short* wpf = (unsigned short*)(ws + (9u << 20) + 84 * 1024); // 64 KB
    float* shiftp       = (float*)(ws + (9u << 20) + 148 * 1024);   // 1 KB

    fold_weights<<<400, 256, 0, stream>>>(
        w_qk, g_qk, b_qk, m_qk, v_qk,
        w_v, g_v, b_v, m_v, v_v,
        w_p, g_p, b_p, m_p, v_p,
        wf1, shift1, wpf, shiftp);

    proj_qkv<<<dim3(64, 4), 256, 0, stream>>>(x, wf1, shift1, qkT, Vt);

    attn_kernel<<<dim3(64, 4), 512, 0, stream>>>(qkT, Vt, xxb);

    proj_out<<<dim3(4, 64, 4), 256, 0, stream>>>(xxb, wpf, shiftp, (float*)d_out);
}

// Round 14
// 69.909 us; speedup vs baseline: 2.3604x; 1.0297x over previous
//
#include <hip/hip_runtime.h>
#include <cstdint>
#include <cstddef>

// ---------------------------------------------------------------------------
// Attention_Param_sharing_Kv_sharing: B=4, C=256, H=W=64 (N=4096), KD=16,
// NH=8, DH=128.  Gram-matrix attention, one shared KV head.
//
// R13 (verified, 72.0us total / 43.2 attn): swapped 32x32x16 flash + K-reg
//   prefetch + defer-max.  attn near pipe-sum saturation; ~29us in edges.
// R14:
//   (1) proj_out FUSED into attn epilogue: merged O rows -> LDS [64][136]
//       f16 (272B stride = free 2-way banks), barrier, in-block 256x64x128
//       GEMM (transcribed from verified proj_out, B re-pointed at LDS).
//   (2) exp2-domain softmax: qk weights pre-scaled by sqrt(log2 e) at fold
//       -> S arrives x log2(e); __expf -> exp2f (saves v_mul per exp);
//       defer THR = 8*log2(e) = 11.54.
//   (3) proj_qkv 512 thr: wave-halves split 9 o-tiles 5/4 (2 waves/SIMD on
//       the latency-exposed x loads; no reduction).
// ---------------------------------------------------------------------------

typedef __attribute__((ext_vector_type(4)))  float f32x4;
typedef __attribute__((ext_vector_type(16))) float f32x16;
typedef __attribute__((ext_vector_type(8)))  _Float16 half8;
typedef __attribute__((ext_vector_type(8)))  unsigned short ushort8;
typedef __attribute__((ext_vector_type(2)))  unsigned u32x2;
typedef __attribute__((ext_vector_type(4)))  unsigned u32x4;

#define N_SP 4096
#define CIN  256
#define KDIM 16
#define DHV  128

__device__ __forceinline__ unsigned short f2h(float f) {
    _Float16 h = (_Float16)f;             // RNE
    return __builtin_bit_cast(unsigned short, h);
}
__device__ __forceinline__ float h2f(unsigned short u) {
    return (float)__builtin_bit_cast(_Float16, u);
}
__device__ __forceinline__ unsigned pk2(float a, float b) {
    return (unsigned)f2h(a) | ((unsigned)f2h(b) << 16);
}
__device__ __forceinline__ unsigned shfl32u(unsigned v, int src) {
    return (unsigned)__shfl((int)v, src, 64);
}
__device__ __forceinline__ f32x4 mfma16(ushort8 a, ushort8 b, f32x4 c) {
    return __builtin_amdgcn_mfma_f32_16x16x32_f16(
        __builtin_bit_cast(half8, a), __builtin_bit_cast(half8, b), c, 0, 0, 0);
}
__device__ __forceinline__ f32x16 mfma32(half8 a, half8 b, f32x16 c) {
    return __builtin_amdgcn_mfma_f32_32x32x16_f16(a, b, c, 0, 0, 0);
}

// ---------------------------------------------------------------------------
// Kernel 0: fold BN into weights.  qk rows pre-scaled by sqrt(log2 e) so
// S = qk.qk arrives multiplied by log2(e) (exp2-domain softmax downstream).
// ---------------------------------------------------------------------------
__global__ __launch_bounds__(256) void fold_weights(
    const float* __restrict__ w_qk, const float* __restrict__ g_qk,
    const float* __restrict__ b_qk, const float* __restrict__ m_qk,
    const float* __restrict__ v_qk,
    const float* __restrict__ w_v, const float* __restrict__ g_v,
    const float* __restrict__ b_v, const float* __restrict__ m_v,
    const float* __restrict__ v_v,
    const float* __restrict__ w_p, const float* __restrict__ g_p,
    const float* __restrict__ b_p, const float* __restrict__ m_p,
    const float* __restrict__ v_p,
    unsigned short* __restrict__ wf1, float* __restrict__ shift1,
    unsigned short* __restrict__ wpf, float* __restrict__ shiftp)
{
    const float SQL2E = 1.2011224087864498f;   // sqrt(log2 e)
    int row = blockIdx.x;
    int t   = threadIdx.x;
    if (row < 144) {
        float s, sh; const float* src;
        if (row < KDIM) {
            s  = g_qk[row] * rsqrtf(v_qk[row] + 1e-5f);
            sh = b_qk[row] - m_qk[row] * s;
            s *= SQL2E; sh *= SQL2E;           // exp2-domain pre-scale
            src = w_qk + row * CIN;
        } else {
            int o = row - KDIM;
            s  = g_v[o] * rsqrtf(v_v[o] + 1e-5f);
            sh = b_v[o] - m_v[o] * s;
            src = w_v + o * CIN;
        }
        wf1[row * CIN + t] = f2h(src[t] * s);
        if (t == 0) shift1[row] = sh;
    } else {
        int o = row - 144;
        float s = g_p[o] * rsqrtf(v_p[o] + 1e-5f);
        if (t < DHV) wpf[o * DHV + t] = f2h(w_p[o * DHV + t] * s);
        if (t == 0) shiftp[o] = b_p[o] - m_p[o] * s;
    }
}

// ---------------------------------------------------------------------------
// Kernel 1: projection GEMM (x read once).  512 thr = 8 waves; wave-halves
// split the 9 o-tiles 5/4 -> 2 waves/SIMD on the latency-exposed x loads.
// ---------------------------------------------------------------------------
__global__ __launch_bounds__(512) void proj_qkv(
    const float* __restrict__ x,
    const unsigned short* __restrict__ wf1, const float* __restrict__ shift1,
    unsigned short* __restrict__ qkT, unsigned short* __restrict__ Vt)
{
    const int b  = blockIdx.y;
    const int n0 = blockIdx.x * 64;
    const int tid  = threadIdx.x;
    const int w    = tid >> 6;
    const int half = w >> 2;           // o-half: 0 -> ot 0..4, 1 -> ot 5..8
    const int wq   = w & 3;            // n-subtile
    const int lane = tid & 63;
    const int lg   = lane >> 4;
    const int lr   = lane & 15;
    const int n    = n0 + wq * 16 + lr;

    const float* xb = x + (size_t)b * CIN * N_SP;

    if (half == 0) {
        f32x4 acc[5];
#pragma unroll
        for (int i = 0; i < 5; ++i) acc[i] = (f32x4){0.f, 0.f, 0.f, 0.f};
        for (int ks = 0; ks < 8; ++ks) {
            const int cbase = ks * 32 + lg * 8;
            ushort8 bx;
#pragma unroll
            for (int j = 0; j < 8; ++j)
                bx[j] = f2h(xb[(size_t)(cbase + j) * N_SP + n]);
#pragma unroll
            for (int i = 0; i < 5; ++i) {
                ushort8 a = *(const ushort8*)(wf1 + (i * 16 + lr) * CIN + cbase);
                acc[i] = mfma16(a, bx, acc[i]);
            }
        }
#pragma unroll
        for (int i = 0; i < 5; ++i)
#pragma unroll
            for (int r = 0; r < 4; ++r) {
                int o = i * 16 + lg * 4 + r;
                float val = acc[i][r] + shift1[o];
                unsigned short hv = f2h(val);
                if (o < KDIM) qkT[((size_t)b * N_SP + n) * 16 + o] = hv;
                else          Vt[((size_t)b * DHV + (o - KDIM)) * N_SP + n] = hv;
            }
    } else {
        f32x4 acc[4];
#pragma unroll
        for (int i = 0; i < 4; ++i) acc[i] = (f32x4){0.f, 0.f, 0.f, 0.f};
        for (int ks = 0; ks < 8; ++ks) {
            const int cbase = ks * 32 + lg * 8;
            ushort8 bx;
#pragma unroll
            for (int j = 0; j < 8; ++j)
                bx[j] = f2h(xb[(size_t)(cbase + j) * N_SP + n]);
#pragma unroll
            for (int i = 0; i < 4; ++i) {
                ushort8 a = *(const ushort8*)(wf1 + ((i + 5) * 16 + lr) * CIN + cbase);
                acc[i] = mfma16(a, bx, acc[i]);
            }
        }
#pragma unroll
        for (int i = 0; i < 4; ++i)
#pragma unroll
            for (int r = 0; r < 4; ++r) {
                int o = (i + 5) * 16 + lg * 4 + r;
                float val = acc[i][r] + shift1[o];
                Vt[((size_t)b * DHV + (o - KDIM)) * N_SP + n] = f2h(val);
            }
    }
}

// ---------------------------------------------------------------------------
// Stage one 64-key V tile (128 d x 64 halves = 16 KB) via global_load_lds,
// 16 x 1KB chunks; wave p of the stream issues chunks [p*8, p*8+8).
// Source pre-swizzled (rule 21): physical 16B slot s of row d holds
// logical slot s ^ (d&7).
// ---------------------------------------------------------------------------
__device__ __forceinline__ void stage_v(
    const unsigned short* __restrict__ vt_b,
    unsigned short* v_l, int k0, int p, int lane)
{
#pragma unroll
    for (int s = 0; s < 8; ++s) {
        const int vi = p * 8 + s;
        const int d  = vi * 8 + (lane >> 3);
        const int c8 = (lane & 7) ^ ((lane >> 3) & 7);
        const unsigned short* src = vt_b + (size_t)d * N_SP + k0 + c8 * 8;
        __builtin_amdgcn_global_load_lds(
            (const __attribute__((address_space(1))) void*)src,
            (__attribute__((address_space(3))) void*)(v_l + vi * 512),
            16, 0, 0);
    }
}

// V A-frag for PV: A[m=d][k]: lane&31 = d-row, k = (lane>>5)*8 + j.
__device__ __forceinline__ half8 ldv(const unsigned short* vl, int nb, int kc,
                                     int la31, int hi)
{
    const int d = nb * 32 + la31;
    const ushort8 v = *(const ushort8*)
        (vl + d * 64 + (((kc * 2 + hi) ^ (d & 7)) << 3));
    return __builtin_bit_cast(half8, v);
}

// K A-frag for S: A[m=key][k]: lane&31 = key-row, k = (lane>>5)*8 + j.
__device__ __forceinline__ half8 ldk(const unsigned short* qk_b, int krow,
                                     int la31, int hi)
{
    return __builtin_bit_cast(half8,
        *(const ushort8*)(qk_b + (size_t)(krow + la31) * 16 + hi * 8));
}

// ---------------------------------------------------------------------------
// Kernel 2: flash attention + fused output projection.
// Grid (64, B), 512 thr = 8 waves = 4 streams x 2 waves.  Stream s: keys
// [s*1024,(s+1)*1024), wave p of stream: queries q0+p*32 .. +31.
// exp2-domain softmax (S pre-scaled by log2 e).  After the merge, the 64
// output rows go to LDS [64][136] f16 and all 8 waves run the 256x64x128
// output projection GEMM, storing fp32 to d_out directly.
// ---------------------------------------------------------------------------
__global__ __launch_bounds__(512, 2) void attn_kernel(
    const unsigned short* __restrict__ qkT,   // [b][n][16] f16 (x sqrt(log2e))
    const unsigned short* __restrict__ Vt,    // [b][128][n] f16
    const unsigned short* __restrict__ wpf,   // [256][128] f16
    const float* __restrict__ shiftp,         // [256] f32
    float* __restrict__ out)                  // [b][256][4096] f32
{
    const int b  = blockIdx.y;
    const int q0 = blockIdx.x * 64;
    const int tid  = threadIdx.x;
    const int ws   = tid >> 6;
    const int strm = ws >> 1;          // key-stream 0..3
    const int p    = ws & 1;           // q-half 0..1
    const int lane = tid & 63;
    const int la31 = lane & 31;
    const int hi   = lane >> 5;

    const unsigned short* qk_b = qkT + (size_t)b * N_SP * 16;
    const unsigned short* vt_b = Vt  + (size_t)b * DHV * N_SP;
    const int kbase = strm * (N_SP / 4);
    const int qrow  = q0 + p * 32;

    // Q B-frag (col n = query = lane&31, k = hi*8+j)
    const half8 aq = __builtin_bit_cast(half8,
        *(const ushort8*)(qk_b + (size_t)(qrow + la31) * 16 + hi * 8));

    f32x16 acc0, acc1, acc2, acc3, z16;
#pragma unroll
    for (int i = 0; i < 16; ++i) { z16[i] = 0.f; }
    acc0 = z16; acc1 = z16; acc2 = z16; acc3 = z16;
    float m_r = -__builtin_inff();
    float l_r = 0.f;

    __shared__ __align__(16) unsigned short v_lds[4][2][128 * 64];  // 128 KB
    __shared__ float lmbuf[4][64][2];                               // 2 KB

    stage_v(vt_b, &v_lds[strm][0][0], kbase, p, lane);
    // K register prefetch for tile 0
    half8 kf0n = ldk(qk_b, kbase, la31, hi);
    half8 kf1n = ldk(qk_b, kbase + 32, la31, hi);

    for (int t = 0; t < 16; ++t) {
        const int cur = t & 1;
        __syncthreads();            // buf[cur] + kf*n ready; prior reads done
        if (t < 15)
            stage_v(vt_b, &v_lds[strm][cur ^ 1][0], kbase + (t + 1) * 64,
                    p, lane);
        const half8 kf0 = kf0n;
        const half8 kf1 = kf1n;
        if (t < 15) {               // prefetch K for tile t+1
            kf0n = ldk(qk_b, kbase + (t + 1) * 64, la31, hi);
            kf1n = ldk(qk_b, kbase + (t + 1) * 64 + 32, la31, hi);
        }
        const unsigned short* vl = &v_lds[strm][cur][0];

        // ---- S' = (K Q^T) * log2e (pre-scaled weights) --------------------
        f32x16 s0 = mfma32(kf0, aq, z16);     // keys k0..k0+31
        f32x16 s1 = mfma32(kf1, aq, z16);     // keys k0+32..k0+63

        // ---- in-lane softmax, 2-domain ------------------------------------
        float mpair[8];
#pragma unroll
        for (int i = 0; i < 8; ++i)
            mpair[i] = fmaxf(fmaxf(s0[i], s0[i + 8]), fmaxf(s1[i], s1[i + 8]));
        float mx = fmaxf(fmaxf(fmaxf(mpair[0], mpair[1]), fmaxf(mpair[2], mpair[3])),
                         fmaxf(fmaxf(mpair[4], mpair[5]), fmaxf(mpair[6], mpair[7])));
        mx = fmaxf(mx, __shfl(mx, lane ^ 32));   // other 32 keys on lane^32

        // defer-max: THR = 8*log2e = 11.54 (P <= 2^11.54 = e^8, fp16-safe)
        if (!__all(mx <= m_r + 11.54f)) {
            float mnew = fmaxf(m_r, mx);
            float sc = exp2f(m_r - mnew);         // first tile: exp2(-inf)=0
            l_r *= sc;
#pragma unroll
            for (int i = 0; i < 16; ++i) {
                acc0[i] *= sc; acc1[i] *= sc; acc2[i] *= sc; acc3[i] *= sc;
            }
            m_r = mnew;
        }
#pragma unroll
        for (int i = 0; i < 16; ++i) s0[i] = exp2f(s0[i] - m_r);
#pragma unroll
        for (int i = 0; i < 16; ++i) s1[i] = exp2f(s1[i] - m_r);
        float rpair[8];
#pragma unroll
        for (int i = 0; i < 8; ++i)
            rpair[i] = (s0[i] + s0[i + 8]) + (s1[i] + s1[i + 8]);
        l_r += ((rpair[0] + rpair[1]) + (rpair[2] + rpair[3]))
             + ((rpair[4] + rpair[5]) + (rpair[6] + rpair[7]));

        // ---- O += V^T P : A = V (m=d), B = P (n=query) --------------------
#define PV_CHUNK(SV, B0, KC)                                               \
        {                                                                  \
            unsigned a0 = pk2(SV[B0 + 0], SV[B0 + 1]);                     \
            unsigned a1 = pk2(SV[B0 + 2], SV[B0 + 3]);                     \
            unsigned a2 = pk2(SV[B0 + 4], SV[B0 + 5]);                     \
            unsigned a3 = pk2(SV[B0 + 6], SV[B0 + 7]);                     \
            unsigned p0 = shfl32u(a0, lane ^ 32);                          \
            unsigned p1 = shfl32u(a1, lane ^ 32);                          \
            unsigned p2 = shfl32u(a2, lane ^ 32);                          \
            unsigned p3 = shfl32u(a3, lane ^ 32);                          \
            u32x4 pw;                                                      \
            pw.x = hi ? p2 : a0;                                           \
            pw.y = hi ? p3 : a1;                                           \
            pw.z = hi ? a2 : p0;                                           \
            pw.w = hi ? a3 : p1;                                           \
            half8 pb = __builtin_bit_cast(half8, pw);                      \
            acc0 = mfma32(ldv(vl, 0, KC, la31, hi), pb, acc0);             \
            acc1 = mfma32(ldv(vl, 1, KC, la31, hi), pb, acc1);             \
            acc2 = mfma32(ldv(vl, 2, KC, la31, hi), pb, acc2);             \
            acc3 = mfma32(ldv(vl, 3, KC, la31, hi), pb, acc3);             \
        }
        PV_CHUNK(s0, 0, 0)
        PV_CHUNK(s0, 8, 1)
        PV_CHUNK(s1, 0, 2)
        PV_CHUNK(s1, 8, 3)
#undef PV_CHUNK
    }

    // ---- finish l: other half of the keys lives on lane^32 ---------------
    l_r = l_r + __shfl(l_r, lane ^ 32);

    __syncthreads();   // all streams done reading V bufs -> safe to reuse

    // ---- publish normalized partial O (fp16) + (m,l) ---------------------
    unsigned short* Opart = &v_lds[0][0][0];  // [4 streams][64 q][128 d] f16
    const int qib = p * 32 + la31;
    if (hi == 0) {
        lmbuf[strm][qib][0] = m_r;
        lmbuf[strm][qib][1] = l_r;
    }
    {
        const float invl = 1.0f / l_r;
        const size_t qoff = ((size_t)strm * 64 + qib) * 128;
#define PUB(ACC, NB)                                                       \
        {                                                                  \
            _Pragma("unroll")                                              \
            for (int rq = 0; rq < 4; ++rq) {                               \
                float v0 = ACC[rq * 4 + 0] * invl;                         \
                float v1 = ACC[rq * 4 + 1] * invl;                         \
                float v2 = ACC[rq * 4 + 2] * invl;                         \
                float v3 = ACC[rq * 4 + 3] * invl;                         \
                u32x2 wv; wv.x = pk2(v0, v1); wv.y = pk2(v2, v3);          \
                *(u32x2*)(Opart + qoff + NB * 32 + rq * 8 + 4 * hi) = wv;  \
            }                                                              \
        }
        PUB(acc0, 0) PUB(acc1, 1) PUB(acc2, 2) PUB(acc3, 3)
#undef PUB
    }
    __syncthreads();

    // ---- merge 4 streams -> olds[64][136] f16 (272B stride: 2-way banks) --
    unsigned short* olds = &v_lds[2][0][0];   // 17.4 KB, dead V region
    {
        const int q    = tid >> 3;
        const int dseg = (tid & 7) * 16;
        const float m0 = lmbuf[0][q][0], l0 = lmbuf[0][q][1];
        const float m1 = lmbuf[1][q][0], l1 = lmbuf[1][q][1];
        const float m2 = lmbuf[2][q][0], l2 = lmbuf[2][q][1];
        const float m3 = lmbuf[3][q][0], l3 = lmbuf[3][q][1];
        const float M = fmaxf(fmaxf(m0, m1), fmaxf(m2, m3));
        float w0 = l0 * exp2f(m0 - M);
        float w1 = l1 * exp2f(m1 - M);
        float w2 = l2 * exp2f(m2 - M);
        float w3 = l3 * exp2f(m3 - M);
        const float inv = 1.0f / (w0 + w1 + w2 + w3);
        w0 *= inv; w1 *= inv; w2 *= inv; w3 *= inv;

        const ushort8 A0 = *(const ushort8*)(Opart + (0 * 64 + q) * 128 + dseg);
        const ushort8 A1 = *(const ushort8*)(Opart + (1 * 64 + q) * 128 + dseg);
        const ushort8 A2 = *(const ushort8*)(Opart + (2 * 64 + q) * 128 + dseg);
        const ushort8 A3 = *(const ushort8*)(Opart + (3 * 64 + q) * 128 + dseg);
        const ushort8 B0 = *(const ushort8*)(Opart + (0 * 64 + q) * 128 + dseg + 8);
        const ushort8 B1 = *(const ushort8*)(Opart + (1 * 64 + q) * 128 + dseg + 8);
        const ushort8 B2 = *(const ushort8*)(Opart + (2 * 64 + q) * 128 + dseg + 8);
        const ushort8 B3 = *(const ushort8*)(Opart + (3 * 64 + q) * 128 + dseg + 8);

        ushort8 o0, o1;
#pragma unroll
        for (int i = 0; i < 8; ++i) {
            float va = w0 * h2f(A0[i]) + w1 * h2f(A1[i])
                     + w2 * h2f(A2[i]) + w3 * h2f(A3[i]);
            float vb = w0 * h2f(B0[i]) + w1 * h2f(B1[i])
                     + w2 * h2f(B2[i]) + w3 * h2f(B3[i]);
            o0[i] = f2h(fmaxf(va, 0.f));    // relu
            o1[i] = f2h(fmaxf(vb, 0.f));
        }
        *(ushort8*)(olds + q * 136 + dseg)     = o0;
        *(ushort8*)(olds + q * 136 + dseg + 8) = o1;
    }
    __syncthreads();

    // ---- fused output projection: out[b][256][q0..q0+64) ------------------
    // Wave ws: o-tiles {ws*32, ws*32+16}.  Transcribed from verified
    // proj_out; B-frag from olds (LDS), A-frag from wpf (L2).
    {
        const int lr16 = lane & 15;
        const int lg16 = lane >> 4;
        const int ob   = ws * 32;

        f32x4 pacc[2][4];
#pragma unroll
        for (int i = 0; i < 2; ++i)
#pragma unroll
            for (int j = 0; j < 4; ++j) pacc[i][j] = (f32x4){0.f, 0.f, 0.f, 0.f};

        for (int ks = 0; ks < 4; ++ks) {
            ushort8 a0 = *(const ushort8*)
                (wpf + (size_t)(ob + lr16) * DHV + ks * 32 + lg16 * 8);
            ushort8 a1 = *(const ushort8*)
                (wpf + (size_t)(ob + 16 + lr16) * DHV + ks * 32 + lg16 * 8);
#pragma unroll
            for (int qt = 0; qt < 4; ++qt) {
                ushort8 bfr = *(const ushort8*)
                    (olds + (qt * 16 + lr16) * 136 + ks * 32 + lg16 * 8);
                pacc[0][qt] = mfma16(a0, bfr, pacc[0][qt]);
                pacc[1][qt] = mfma16(a1, bfr, pacc[1][qt]);
            }
        }

#pragma unroll
        for (int t2 = 0; t2 < 2; ++t2)
#pragma unroll
            for (int qt = 0; qt < 4; ++qt)
#pragma unroll
                for (int r = 0; r < 4; ++r) {
                    int o = ob + t2 * 16 + lg16 * 4 + r;
                    out[((size_t)b * CIN + o) * N_SP + q0 + qt * 16 + lr16]
                        = pacc[t2][qt][r] + shiftp[o];
                }
    }
}

// ---------------------------------------------------------------------------
extern "C" void kernel_launch(void* const* d_in, const int* in_sizes, int n_in,
                              void* d_out, int out_size, void* d_ws, size_t ws_size,
                              hipStream_t stream)
{
    const float* x    = (const float*)d_in[0];
    const float* w_qk = (const float*)d_in[2];
    const float* g_qk = (const float*)d_in[3];
    const float* b_qk = (const float*)d_in[4];
    const float* m_qk = (const float*)d_in[5];
    const float* v_qk = (const float*)d_in[6];
    const float* w_v  = (const float*)d_in[7];
    const float* g_v  = (const float*)d_in[8];
    const float* b_v  = (const float*)d_in[9];
    const float* m_v  = (const float*)d_in[10];
    const float* v_v  = (const float*)d_in[11];
    const float* w_p  = (const float*)d_in[12];
    const float* g_p  = (const float*)d_in[13];
    const float* b_p  = (const float*)d_in[14];
    const float* m_p  = (const float*)d_in[15];
    const float* v_p  = (const float*)d_in[16];

    char* ws = (char*)d_ws;
    unsigned short* qkT = (unsigned short*)(ws);                    // 512 KB
    unsigned short* Vt  = (unsigned short*)(ws + (1u << 20));       // 4 MB
    unsigned short* wf1 = (unsigned short*)(ws + (9u << 20));       // 72 KB
    float* shift1       = (float*)(ws + (9u << 20) + 80 * 1024);    // 576 B
    unsigned short* wpf = (unsigned short*)(ws + (9u << 20) + 84 * 1024); // 64 KB
    float* shiftp       = (float*)(ws + (9u << 20) + 148 * 1024);   // 1 KB

    fold_weights<<<400, 256, 0, stream>>>(
        w_qk, g_qk, b_qk, m_qk, v_qk,
        w_v, g_v, b_v, m_v, v_v,
        w_p, g_p, b_p, m_p, v_p,
        wf1, shift1, wpf, shiftp);

    proj_qkv<<<dim3(64, 4), 512, 0, stream>>>(x, wf1, shift1, qkT, Vt);

    attn_kernel<<<dim3(64, 4), 512, 0, stream>>>(
        qkT, Vt, wpf, shiftp, (float*)d_out);
}